// Round 11
// baseline (1192.754 us; speedup 1.0000x reference)
//
#include <hip/hip_runtime.h>
#include <hip/hip_bf16.h>

// Problem constants
#define BSZ   2
#define TSEQ  2048
#define CDIM  4096
#define NH    32
#define NKV   8
#define GQ    4
#define DH    128
#define BT    (BSZ * TSEQ)   // 4096

typedef short   bf16x8  __attribute__((ext_vector_type(8)));
typedef float   f32x4   __attribute__((ext_vector_type(4)));
typedef unsigned short ushort8v __attribute__((ext_vector_type(8)));
typedef unsigned short u16;

#define LDS_AS(p) ((__attribute__((address_space(3))) void*)(p))
#define GLB_AS(p) ((const __attribute__((address_space(1))) void*)(p))

static __device__ inline unsigned short bf16_bits(float f) {
  __hip_bfloat16 h = __float2bfloat16(f);
  return *(unsigned short*)&h;
}
static __device__ inline float bits_f32(unsigned short u) {
  unsigned v = ((unsigned)u) << 16;
  return __builtin_bit_cast(float, v);
}

// ---------------- fp32 -> bf16 elementwise ----------------
__global__ __launch_bounds__(256) void cvt_bf16x4(
    const float* __restrict__ src, __hip_bfloat16* __restrict__ dst, int n4) {
  int i = blockIdx.x * 256 + threadIdx.x;
  if (i >= n4) return;
  float4 v = ((const float4*)src)[i];
  ushort4 o;
  o.x = bf16_bits(v.x); o.y = bf16_bits(v.y);
  o.z = bf16_bits(v.z); o.w = bf16_bits(v.w);
  ((ushort4*)dst)[i] = o;
}

// ---------------- transpose + convert: src K x N fp32 -> dst N x K bf16 ----------------
__global__ __launch_bounds__(256) void transpose_cvt(
    const float* __restrict__ src, __hip_bfloat16* __restrict__ dst, int K, int N) {
  __shared__ float T[64][65];
  const int bn = blockIdx.x * 64;
  const int bk = blockIdx.y * 64;
  const int tid = threadIdx.x;
  for (int i = tid; i < 64 * 16; i += 256) {
    int r = i >> 4, c4 = i & 15;
    float4 v = *(const float4*)&src[(size_t)(bk + r) * N + bn + c4 * 4];
    T[r][c4*4+0] = v.x; T[r][c4*4+1] = v.y; T[r][c4*4+2] = v.z; T[r][c4*4+3] = v.w;
  }
  __syncthreads();
  for (int i = tid; i < 64 * 16; i += 256) {
    int n = i >> 4, k4 = i & 15;
    ushort4 o;
    o.x = bf16_bits(T[k4*4+0][n]); o.y = bf16_bits(T[k4*4+1][n]);
    o.z = bf16_bits(T[k4*4+2][n]); o.w = bf16_bits(T[k4*4+3][n]);
    *(ushort4*)&dst[(size_t)(bn + n) * K + bk + k4 * 4] = o;
  }
}

// ---------------- bf16 MFMA GEMM (m97 structure) — kept for KV GEMM (N=2048) ----------------
__global__ __launch_bounds__(256) void gemm_mfma(
    const __hip_bfloat16* __restrict__ A, const __hip_bfloat16* __restrict__ Bt,
    void* __restrict__ C, int N, int K, int outBf16) {
  __shared__ __hip_bfloat16 As[128 * 32];
  __shared__ __hip_bfloat16 Bs[128 * 32];
  const int tid  = threadIdx.x;
  const int lane = tid & 63;
  const int wv   = tid >> 6;
  const int row0 = blockIdx.y * 128;
  const int col0 = blockIdx.x * 128;
  const int wm   = (wv & 1) * 64;
  const int wn   = (wv >> 1) * 64;
  const int lrow = lane & 15;
  const int kgrp = lane >> 4;

  f32x4 zero = {0.f, 0.f, 0.f, 0.f};
  f32x4 acc[4][4];
  #pragma unroll
  for (int mi = 0; mi < 4; ++mi)
    #pragma unroll
    for (int ni = 0; ni < 4; ++ni) acc[mi][ni] = zero;

  for (int k0 = 0; k0 < K; k0 += 32) {
    #pragma unroll
    for (int r = 0; r < 2; ++r) {
      int idx16 = r * 256 + tid;
      int arow  = idx16 >> 2;
      int akk   = (idx16 & 3) << 3;
      const __hip_bfloat16* ga = &A [(size_t)(row0 + arow) * K + k0 + akk];
      const __hip_bfloat16* gb = &Bt[(size_t)(col0 + arow) * K + k0 + akk];
      char* la = (char*)As + (r * 4096 + wv * 1024 + lane * 16);
      char* lb = (char*)Bs + (r * 4096 + wv * 1024 + lane * 16);
      __builtin_amdgcn_global_load_lds(GLB_AS(ga), LDS_AS(la), 16, 0, 0);
      __builtin_amdgcn_global_load_lds(GLB_AS(gb), LDS_AS(lb), 16, 0, 0);
    }
    __syncthreads();
    bf16x8 af[4], bfr[4];
    #pragma unroll
    for (int i = 0; i < 4; ++i) {
      af[i]  = *(const bf16x8*)&As[(wm + i * 16 + lrow) * 32 + kgrp * 8];
      bfr[i] = *(const bf16x8*)&Bs[(wn + i * 16 + lrow) * 32 + kgrp * 8];
    }
    #pragma unroll
    for (int mi = 0; mi < 4; ++mi)
      #pragma unroll
      for (int ni = 0; ni < 4; ++ni)
        acc[mi][ni] = __builtin_amdgcn_mfma_f32_16x16x32_bf16(af[mi], bfr[ni], acc[mi][ni], 0, 0, 0);
    __syncthreads();
  }

  if (outBf16) {
    __hip_bfloat16* Cb = (__hip_bfloat16*)C;
    #pragma unroll
    for (int mi = 0; mi < 4; ++mi)
      #pragma unroll
      for (int ni = 0; ni < 4; ++ni) {
        int col = col0 + wn + ni * 16 + lrow;
        int rowb = row0 + wm + mi * 16 + kgrp * 4;
        #pragma unroll
        for (int r = 0; r < 4; ++r)
          Cb[(size_t)(rowb + r) * N + col] = __float2bfloat16(acc[mi][ni][r]);
      }
  } else {
    float* Cf = (float*)C;
    #pragma unroll
    for (int mi = 0; mi < 4; ++mi)
      #pragma unroll
      for (int ni = 0; ni < 4; ++ni) {
        int col = col0 + wn + ni * 16 + lrow;
        int rowb = row0 + wm + mi * 16 + kgrp * 4;
        #pragma unroll
        for (int r = 0; r < 4; ++r)
          Cf[(size_t)(rowb + r) * N + col] = acc[mi][ni][r];
      }
  }
}

// ---------------- 256x256 8-phase bf16 MFMA GEMM (m201 template, plain HIP) ----------------
__global__ __launch_bounds__(512, 2) void gemm256(
    const __hip_bfloat16* __restrict__ A, const __hip_bfloat16* __restrict__ Bt,
    void* __restrict__ C, int N, int K, int outBf16) {
  __shared__ __hip_bfloat16 AsBuf[2][16384];   // [buf][256 rows x 64 k]
  __shared__ __hip_bfloat16 BsBuf[2][16384];

  const int tid  = threadIdx.x;
  const int lane = tid & 63;
  const int wid  = tid >> 6;
  const int wm   = wid >> 2;        // 0..1
  const int wn   = wid & 3;         // 0..3
  const int quad = lane >> 4;
  const int l15  = lane & 15;

  // XCD-aware block swizzle (bijective when nwg % 8 == 0)
  const int nbx = N >> 8;
  int bid = blockIdx.y * nbx + blockIdx.x;
  const int nwg = nbx * (int)gridDim.y;
  if ((nwg & 7) == 0) bid = (bid & 7) * (nwg >> 3) + (bid >> 3);
  const int row0 = (bid / nbx) << 8;
  const int col0 = (bid % nbx) << 8;

  const int NT = K >> 6;

  // fragment-read element offsets (swizzled): row&7 == l15&7 for all frag rows
  const int xr  = (l15 & 7) << 4;                  // byte XOR, bits 4-6
  const int ke0 = (((quad * 16)      ^ xr) >> 1);  // kc=0, elements
  const int ke1 = (((64 + quad * 16) ^ xr) >> 1);  // kc=1
  const int arE = (wm * 128 + l15) * 64;           // A row base, elements
  const int brE = (wn * 64  + l15) * 64;           // B row base, elements

  // Stage one 128-row half-tile (16 KiB): linear LDS dest, inverse-swizzled global src.
#define STG(srcp, r0g, ldsb, h, k0e) do {                                          \
    _Pragma("unroll")                                                              \
    for (int j = 0; j < 2; ++j) {                                                  \
      int p    = (j * 512 + tid) << 4;               /* byte in half-tile */       \
      int prow = p >> 7;                                                           \
      int koff = (p & 127) ^ ((prow & 7) << 4);                                    \
      const __hip_bfloat16* gsrc =                                                 \
          (srcp) + (size_t)((r0g) + (h) * 128 + prow) * K + (k0e) + (koff >> 1);   \
      char* ldst = (char*)(ldsb) + (h) * 16384 + p;                                \
      __builtin_amdgcn_global_load_lds(GLB_AS(gsrc), LDS_AS(ldst), 16, 0, 0);      \
    }                                                                              \
  } while (0)

  f32x4 acc[8][4];
  #pragma unroll
  for (int i = 0; i < 8; ++i)
    #pragma unroll
    for (int j = 0; j < 4; ++j) acc[i][j] = (f32x4){0.f, 0.f, 0.f, 0.f};

  // prologue: tile0 complete + tile1 B-halves (A-halves of tile1 come in phases 1-2 of t=0)
  STG(A,  row0, &AsBuf[0][0], 0, 0);
  STG(A,  row0, &AsBuf[0][0], 1, 0);
  STG(Bt, col0, &BsBuf[0][0], 0, 0);
  STG(Bt, col0, &BsBuf[0][0], 1, 0);
  if (NT > 1) {
    STG(Bt, col0, &BsBuf[1][0], 0, 64);
    STG(Bt, col0, &BsBuf[1][0], 1, 64);
    asm volatile("s_waitcnt vmcnt(4)" ::: "memory");   // tile0 landed, tile1 B in flight
  } else {
    asm volatile("s_waitcnt vmcnt(0)" ::: "memory");
  }
  __builtin_amdgcn_s_barrier();

  for (int t = 0; t < NT; ++t) {
    const int d  = t & 1, od = d ^ 1;
    char* Aod = (char*)&AsBuf[od][0];
    char* Bd  = (char*)&BsBuf[d][0];
    const int k1 = (t + 1) << 6, k2 = (t + 2) << 6;
    bf16x8 aH[4][2], b0[2][2], b1[2][2];

    // ---- phase 1 : Q0 = (M0, N0) ; stage A-half0(t+1) into other buf ----
    #pragma unroll
    for (int m = 0; m < 4; ++m) {
      aH[m][0] = *(const bf16x8*)&AsBuf[d][arE + m * 1024 + ke0];
      aH[m][1] = *(const bf16x8*)&AsBuf[d][arE + m * 1024 + ke1];
    }
    #pragma unroll
    for (int n = 0; n < 2; ++n) {
      b0[n][0] = *(const bf16x8*)&BsBuf[d][brE + n * 1024 + ke0];
      b0[n][1] = *(const bf16x8*)&BsBuf[d][brE + n * 1024 + ke1];
    }
    if (t + 1 < NT) STG(A, row0, Aod, 0, k1);
    __builtin_amdgcn_s_barrier();
    asm volatile("s_waitcnt lgkmcnt(0)" ::: "memory");
    __builtin_amdgcn_s_setprio(1);
    #pragma unroll
    for (int m = 0; m < 4; ++m)
      #pragma unroll
      for (int n = 0; n < 2; ++n) {
        acc[m][n] = __builtin_amdgcn_mfma_f32_16x16x32_bf16(aH[m][0], b0[n][0], acc[m][n], 0, 0, 0);
        acc[m][n] = __builtin_amdgcn_mfma_f32_16x16x32_bf16(aH[m][1], b0[n][1], acc[m][n], 0, 0, 0);
      }
    __builtin_amdgcn_s_setprio(0);
    __builtin_amdgcn_s_barrier();

    // ---- phase 2 : Q1 = (M0, N1) ; stage A-half1(t+1) ----
    #pragma unroll
    for (int n = 0; n < 2; ++n) {
      b1[n][0] = *(const bf16x8*)&BsBuf[d][brE + (n + 2) * 1024 + ke0];
      b1[n][1] = *(const bf16x8*)&BsBuf[d][brE + (n + 2) * 1024 + ke1];
    }
    if (t + 1 < NT) STG(A, row0, Aod, 1, k1);
    __builtin_amdgcn_s_barrier();
    asm volatile("s_waitcnt lgkmcnt(0)" ::: "memory");
    __builtin_amdgcn_s_setprio(1);
    #pragma unroll
    for (int m = 0; m < 4; ++m)
      #pragma unroll
      for (int n = 0; n < 2; ++n) {
        acc[m][n + 2] = __builtin_amdgcn_mfma_f32_16x16x32_bf16(aH[m][0], b1[n][0], acc[m][n + 2], 0, 0, 0);
        acc[m][n + 2] = __builtin_amdgcn_mfma_f32_16x16x32_bf16(aH[m][1], b1[n][1], acc[m][n + 2], 0, 0, 0);
      }
    __builtin_amdgcn_s_setprio(0);
    __builtin_amdgcn_s_barrier();

    // ---- phase 3 : Q2 = (M1, N1) ; stage B-half0(t+2) into own buf (B reads done @ph2) ----
    #pragma unroll
    for (int m = 0; m < 4; ++m) {
      aH[m][0] = *(const bf16x8*)&AsBuf[d][arE + 4096 + m * 1024 + ke0];
      aH[m][1] = *(const bf16x8*)&AsBuf[d][arE + 4096 + m * 1024 + ke1];
    }
    if (t + 2 < NT) STG(Bt, col0, Bd, 0, k2);
    __builtin_amdgcn_s_barrier();
    asm volatile("s_waitcnt lgkmcnt(0)" ::: "memory");
    __builtin_amdgcn_s_setprio(1);
    #pragma unroll
    for (int m = 0; m < 4; ++m)
      #pragma unroll
      for (int n = 0; n < 2; ++n) {
        acc[m + 4][n + 2] = __builtin_amdgcn_mfma_f32_16x16x32_bf16(aH[m][0], b1[n][0], acc[m + 4][n + 2], 0, 0, 0);
        acc[m + 4][n + 2] = __builtin_amdgcn_mfma_f32_16x16x32_bf16(aH[m][1], b1[n][1], acc[m + 4][n + 2], 0, 0, 0);
      }
    __builtin_amdgcn_s_setprio(0);
    __builtin_amdgcn_s_barrier();

    // ---- phase 4 : Q3 = (M1, N0) (all frags in regs) ; stage B-half1(t+2) ----
    if (t + 2 < NT) STG(Bt, col0, Bd, 1, k2);
    __builtin_amdgcn_s_barrier();
    __builtin_amdgcn_s_setprio(1);
    #pragma unroll
    for (int m = 0; m < 4; ++m)
      #pragma unroll
      for (int n = 0; n < 2; ++n) {
        acc[m + 4][n] = __builtin_amdgcn_mfma_f32_16x16x32_bf16(aH[m][0], b0[n][0], acc[m + 4][n], 0, 0, 0);
        acc[m + 4][n] = __builtin_amdgcn_mfma_f32_16x16x32_bf16(aH[m][1], b0[n][1], acc[m + 4][n], 0, 0, 0);
      }
    __builtin_amdgcn_s_setprio(0);
    // boundary: tile t+1's A-halves must be landed; keep B(t+2) (4 loads) in flight
    if (t < NT - 2)       asm volatile("s_waitcnt vmcnt(4)" ::: "memory");
    else if (t == NT - 2) asm volatile("s_waitcnt vmcnt(0)" ::: "memory");
    __builtin_amdgcn_s_barrier();
  }
#undef STG

  if (outBf16) {
    __hip_bfloat16* Cb = (__hip_bfloat16*)C;
    #pragma unroll
    for (int mi = 0; mi < 8; ++mi)
      #pragma unroll
      for (int ni = 0; ni < 4; ++ni) {
        int col  = col0 + wn * 64 + ni * 16 + l15;
        int rowb = row0 + wm * 128 + mi * 16 + quad * 4;
        #pragma unroll
        for (int r = 0; r < 4; ++r)
          Cb[(size_t)(rowb + r) * N + col] = __float2bfloat16(acc[mi][ni][r]);
      }
  } else {
    float* Cf = (float*)C;
    #pragma unroll
    for (int mi = 0; mi < 8; ++mi)
      #pragma unroll
      for (int ni = 0; ni < 4; ++ni) {
        int col  = col0 + wn * 64 + ni * 16 + l15;
        int rowb = row0 + wm * 128 + mi * 16 + quad * 4;
        #pragma unroll
        for (int r = 0; r < 4; ++r)
          Cf[(size_t)(rowb + r) * N + col] = acc[mi][ni][r];
      }
  }
}

// ---------------- RoPE on a bf16 buffer ----------------
__global__ __launch_bounds__(256) void rope_bf16(
    __hip_bfloat16* __restrict__ buf, int stride, int perRow,
    const float* __restrict__ cosb, const float* __restrict__ sinb) {
  int idx = blockIdx.x * 256 + threadIdx.x;
  int row = idx / perRow;
  if (row >= BT) return;
  int c8 = (idx - row * perRow) * 8;
  int t  = row & (TSEQ - 1);
  int cp = c8 & (DH - 1);
  __hip_bfloat16* p = buf + (size_t)row * stride + c8;
  ushort8v raw = *(const ushort8v*)p;
  const float* cr = &cosb[(size_t)t * DH + cp];
  const float* sr = &sinb[(size_t)t * DH + cp];
  ushort8v outp;
  #pragma unroll
  for (int j = 0; j < 8; j += 2) {
    float x1 = bits_f32(raw[j]), x2 = bits_f32(raw[j + 1]);
    float c = cr[j], s = sr[j];
    outp[j]     = bf16_bits(x1 * c - x2 * s);
    outp[j + 1] = bf16_bits(x1 * s + x2 * c);
  }
  *(ushort8v*)p = outp;
}

// ---------------- V transpose into dense per-(b,kvh,tile) 128x64 blobs ----------------
__global__ __launch_bounds__(256) void transpose_v(
    const __hip_bfloat16* __restrict__ kvsrc, u16* __restrict__ vt) {
  __shared__ u16 T[64][72];
  const int tid  = threadIdx.x;
  const int tile = blockIdx.x, kvh = blockIdx.y, b = blockIdx.z;
  u16* dst = vt + ((size_t)((b * NKV + kvh) * 32 + tile)) * (128 * 64);
  for (int half = 0; half < 2; ++half) {
    #pragma unroll
    for (int it = 0; it < 2; ++it) {
      int idx = it * 256 + tid;          // 512 chunks = 64 t x 8 d-chunks
      int r = idx >> 3, c8 = idx & 7;
      ushort8v vdat = *(const ushort8v*)&kvsrc[
          (size_t)(b * TSEQ + tile * 64 + r) * 2048 + 1024 + kvh * DH + half * 64 + c8 * 8];
      *(ushort8v*)&T[r][c8 * 8] = vdat;
    }
    __syncthreads();
    #pragma unroll
    for (int it = 0; it < 2; ++it) {
      int idx = it * 256 + tid;
      int d = idx >> 3, c8 = idx & 7;    // d row of output, c8: t-chunk
      ushort8v o8;
      #pragma unroll
      for (int j = 0; j < 8; ++j) o8[j] = T[c8 * 8 + j][d];
      *(ushort8v*)&dst[(size_t)(half * 64 + d) * 64 + c8 * 8] = o8;
    }
    __syncthreads();
  }
}

// ---------------- MFMA flash attention ----------------
// LPT: mtile = gridDim.x-1-blockIdx.x (longest blocks dispatch first -> packed tail).
// V is NOT LDS-staged: PV reads fragments directly from the dense V^T blob
// (16 KB/tile, L2-resident across the 4 GQA heads). LDS = Ks 16KB + Ps 8.5KB
// = 24.5 KB -> 6 blocks/CU LDS-limit (VGPR ~100 -> ~5 waves/SIMD binding).
// K: reg-prefetch (t+1) during compute, XOR-swizzled LDS write at tail.
#define PSTR 68    // Ps row stride

__global__ __launch_bounds__(256) void flash_mfma(
    const __hip_bfloat16* __restrict__ q,    // (BT, 4096)
    const __hip_bfloat16* __restrict__ kv,   // kvb (BT, 2048); k at col kvh*128
    const u16* __restrict__ vt,              // V^T blobs
    __hip_bfloat16* __restrict__ o,          // (BT, 4096)
    const int* __restrict__ causal_p) {
  __shared__ u16 Ks[64 * 128];      // [kv][d], XOR-swizzled
  __shared__ u16 Ps[4][16 * PSTR];  // per-wave [q][kv]

  const int tid  = threadIdx.x;
  const int lane = tid & 63;
  const int wq   = tid >> 6;
  const int quad = lane >> 4;
  const int l15  = lane & 15;
  const int mtile = (int)gridDim.x - 1 - (int)blockIdx.x;   // LPT order
  const int h = blockIdx.y, b = blockIdx.z;
  const int kvh = h >> 2;
  const int m0  = mtile * 64;
  const bool causal = (*causal_p != 0);
  const float NEG_INF = -__builtin_inff();
  const float scale = 0.08838834764831845f;
  const int swz = (l15 & 7) << 3;   // element XOR for this lane's Ks reads

  bf16x8 qf[4];
  {
    const __hip_bfloat16* qrow =
        &q[(size_t)(b * TSEQ + m0 + wq * 16 + l15) * CDIM + h * DH + quad * 8];
    #pragma unroll
    for (int kc = 0; kc < 4; ++kc) qf[kc] = *(const bf16x8*)(qrow + kc * 32);
  }

  f32x4 Ot[8];
  #pragma unroll
  for (int dt = 0; dt < 8; ++dt) Ot[dt] = (f32x4){0.f, 0.f, 0.f, 0.f};
  float mrow[4] = {NEG_INF, NEG_INF, NEG_INF, NEG_INF};
  float lrow[4] = {0.f, 0.f, 0.f, 0.f};

  const int ntiles = causal ? (mtile + 1) : (TSEQ / 64);
  u16* Pw = &Ps[wq][0];
  const u16* vtbase = vt + ((size_t)(b * NKV + kvh) * 32) * (128 * 64);

  ushort8v kreg[4];
  // prologue: stage K tile 0
  #pragma unroll
  for (int it = 0; it < 4; ++it) {
    int idx = it * 256 + tid;
    int r = idx >> 4, c8 = idx & 15;
    kreg[it] = *(const ushort8v*)&kv[(size_t)(b * TSEQ + r) * 2048 + kvh * DH + c8 * 8];
  }
  #pragma unroll
  for (int it = 0; it < 4; ++it) {
    int idx = it * 256 + tid;
    int r = idx >> 4, c8 = idx & 15;
    *(ushort8v*)&Ks[r * 128 + ((c8 ^ (r & 7)) * 8)] = kreg[it];
  }
  __syncthreads();

  for (int tile = 0; tile < ntiles; ++tile) {
    const int j0 = tile * 64;
    // prefetch next K tile into registers (latency hides under compute)
    if (tile + 1 < ntiles) {
      #pragma unroll
      for (int it = 0; it < 4; ++it) {
        int idx = it * 256 + tid;
        int r = idx >> 4, c8 = idx & 15;
        kreg[it] = *(const ushort8v*)&kv[(size_t)(b * TSEQ + j0 + 64 + r) * 2048 + kvh * DH + c8 * 8];
      }
    }

    // S = Q K^T : 4 kv 16-tiles x 4 d-chunks
    f32x4 S[4];
    #pragma unroll
    for (int jt = 0; jt < 4; ++jt) {
      f32x4 acc = {0.f, 0.f, 0.f, 0.f};
      #pragma unroll
      for (int kc = 0; kc < 4; ++kc) {
        bf16x8 kf = *(const bf16x8*)&Ks[(jt * 16 + l15) * 128 + ((kc * 32 + quad * 8) ^ swz)];
        acc = __builtin_amdgcn_mfma_f32_16x16x32_bf16(qf[kc], kf, acc, 0, 0, 0);
      }
      S[jt] = acc;
    }
    #pragma unroll
    for (int jt = 0; jt < 4; ++jt)
      #pragma unroll
      for (int r = 0; r < 4; ++r) S[jt][r] *= scale;
    if (causal && tile == mtile) {
      const int qr0 = m0 + wq * 16 + quad * 4;
      #pragma unroll
      for (int jt = 0; jt < 4; ++jt)
        #pragma unroll
        for (int r = 0; r < 4; ++r)
          if (j0 + jt * 16 + l15 > qr0 + r) S[jt][r] = NEG_INF;
    }

    // online softmax: rows = quad*4+r, cols across 16 lanes of the quad group
    float alpha[4], rsum[4];
    #pragma unroll
    for (int r = 0; r < 4; ++r) {
      float mx = fmaxf(fmaxf(S[0][r], S[1][r]), fmaxf(S[2][r], S[3][r]));
      #pragma unroll
      for (int w = 1; w <= 8; w <<= 1) mx = fmaxf(mx, __shfl_xor(mx, w));
      float mn = fmaxf(mrow[r], mx);
      alpha[r] = __expf(mrow[r] - mn);
      mrow[r] = mn;
      rsum[r] = 0.f;
    }
    #pragma unroll
    for (int jt = 0; jt < 4; ++jt)
      #pragma unroll
      for (int r = 0; r < 4; ++r) {
        float p = __expf(S[jt][r] - mrow[r]);   // masked -> exp(-inf) = 0
        rsum[r] += p;
        Pw[(quad * 4 + r) * PSTR + jt * 16 + l15] = bf16_bits(p);
      }
    #pragma unroll
    for (int r = 0; r < 4; ++r) {
      float s = rsum[r];
      #pragma unroll
      for (int w = 1; w <= 8; w <<= 1) s += __shfl_xor(s, w);
      lrow[r] = lrow[r] * alpha[r] + s;
    }
    // rescale O
    #pragma unroll
    for (int dt = 0; dt < 8; ++dt)
      #pragma unroll
      for (int r = 0; r < 4; ++r) Ot[dt][r] *= alpha[r];

    // O += P V : A = P[m=q][k=kv], B = V^T fragments straight from global blob
    {
      const u16* vblob = vtbase + (size_t)tile * (128 * 64);
      #pragma unroll
      for (int kc = 0; kc < 2; ++kc) {
        bf16x8 pf = *(const bf16x8*)&Pw[l15 * PSTR + kc * 32 + quad * 8];
        bf16x8 vf[8];
        #pragma unroll
        for (int dt = 0; dt < 8; ++dt)
          vf[dt] = *(const bf16x8*)&vblob[(size_t)(dt * 16 + l15) * 64 + kc * 32 + quad * 8];
        #pragma unroll
        for (int dt = 0; dt < 8; ++dt)
          Ot[dt] = __builtin_amdgcn_mfma_f32_16x16x32_bf16(pf, vf[dt], Ot[dt], 0, 0, 0);
      }
    }

    // write next K tile to LDS after all waves finished reading this one
    if (tile + 1 < ntiles) {
      __syncthreads();
      #pragma unroll
      for (int it = 0; it < 4; ++it) {
        int idx = it * 256 + tid;
        int r = idx >> 4, c8 = idx & 15;
        *(ushort8v*)&Ks[r * 128 + ((c8 ^ (r & 7)) * 8)] = kreg[it];
      }
      __syncthreads();
    }
  }

  // epilogue: normalize and store
  float invl[4];
  #pragma unroll
  for (int r = 0; r < 4; ++r) invl[r] = 1.f / lrow[r];
  #pragma unroll
  for (int dt = 0; dt < 8; ++dt)
    #pragma unroll
    for (int r = 0; r < 4; ++r)
      o[(size_t)(b * TSEQ + m0 + wq * 16 + quad * 4 + r) * CDIM + h * DH + dt * 16 + l15] =
          __float2bfloat16(Ot[dt][r] * invl[r]);
}

// ---------------- launch ----------------
extern "C" void kernel_launch(void* const* d_in, const int* in_sizes, int n_in,
                              void* d_out, int out_size, void* d_ws, size_t ws_size,
                              hipStream_t stream) {
  const float* x    = (const float*)d_in[0];
  const float* wq   = (const float*)d_in[1];
  const float* wk   = (const float*)d_in[2];
  const float* wv   = (const float*)d_in[3];
  const float* wo   = (const float*)d_in[4];
  const float* cosb = (const float*)d_in[5];
  const float* sinb = (const float*)d_in[6];
  const int* causal = (const int*)d_in[7];

  char* wsb = (char*)d_ws;
  __hip_bfloat16* xb   = (__hip_bfloat16*)(wsb);
  __hip_bfloat16* woT  = (__hip_bfloat16*)(wsb);
  __hip_bfloat16* wqT  = (__hip_bfloat16*)(wsb + (((size_t)32) << 20));
  __hip_bfloat16* obuf = (__hip_bfloat16*)(wsb + (((size_t)32) << 20));
  __hip_bfloat16* wkvT = (__hip_bfloat16*)(wsb + (((size_t)64) << 20));
  u16*            vtb  = (u16*)           (wsb + (((size_t)64) << 20));
  __hip_bfloat16* kvb  = (__hip_bfloat16*)(wsb + (((size_t)80) << 20));
  __hip_bfloat16* qb   = (__hip_bfloat16*)d_out;

  dim3 blk(256);
  dim3 blk5(512);
  cvt_bf16x4<<<dim3((BT * CDIM / 4 + 255) / 256), blk, 0, stream>>>(x, xb, BT * CDIM / 4);
  transpose_cvt<<<dim3(CDIM / 64, CDIM / 64), blk, 0, stream>>>(wq, wqT, CDIM, CDIM);
  transpose_cvt<<<dim3(1024 / 64, CDIM / 64), blk, 0, stream>>>(wk, wkvT, CDIM, 1024);
  transpose_cvt<<<dim3(1024 / 64, CDIM / 64), blk, 0, stream>>>(wv, wkvT + (size_t)1024 * CDIM, CDIM, 1024);
  gemm256<<<dim3(CDIM / 256, BT / 256), blk5, 0, stream>>>(xb, wqT, qb, CDIM, CDIM, 1);
  gemm_mfma<<<dim3(2048 / 128, BT / 128), blk, 0, stream>>>(xb, wkvT, kvb, 2048, CDIM, 1);
  transpose_v<<<dim3(32, NKV, BSZ), blk, 0, stream>>>(kvb, vtb);
  rope_bf16<<<dim3(BT * (CDIM / 8) / 256), blk, 0, stream>>>(qb, CDIM, CDIM / 8, cosb, sinb);
  rope_bf16<<<dim3(BT * (1024 / 8) / 256), blk, 0, stream>>>(kvb, 2048, 1024 / 8, cosb, sinb);
  transpose_cvt<<<dim3(CDIM / 64, CDIM / 64), blk, 0, stream>>>(wo, woT, CDIM, CDIM);
  flash_mfma<<<dim3(TSEQ / 64, NH, BSZ), blk, 0, stream>>>(qb, kvb, vtb, obuf, causal);
  gemm256<<<dim3(CDIM / 256, BT / 256), blk5, 0, stream>>>(obuf, woT, d_out, CDIM, CDIM, 0);
}

// Round 12
// 1012.684 us; speedup vs baseline: 1.1778x; 1.1778x over previous
//
#include <hip/hip_runtime.h>
#include <hip/hip_bf16.h>

// Problem constants
#define BSZ   2
#define TSEQ  2048
#define CDIM  4096
#define NH    32
#define NKV   8
#define GQ    4
#define DH    128
#define BT    (BSZ * TSEQ)   // 4096

typedef short   bf16x8  __attribute__((ext_vector_type(8)));
typedef float   f32x4   __attribute__((ext_vector_type(4)));
typedef unsigned short ushort8v __attribute__((ext_vector_type(8)));
typedef unsigned short u16;

#define LDS_AS(p) ((__attribute__((address_space(3))) void*)(p))
#define GLB_AS(p) ((const __attribute__((address_space(1))) void*)(p))

static __device__ inline unsigned short bf16_bits(float f) {
  __hip_bfloat16 h = __float2bfloat16(f);
  return *(unsigned short*)&h;
}
static __device__ inline float bits_f32(unsigned short u) {
  unsigned v = ((unsigned)u) << 16;
  return __builtin_bit_cast(float, v);
}

// ---------------- fp32 -> bf16 elementwise ----------------
__global__ __launch_bounds__(256) void cvt_bf16x4(
    const float* __restrict__ src, __hip_bfloat16* __restrict__ dst, int n4) {
  int i = blockIdx.x * 256 + threadIdx.x;
  if (i >= n4) return;
  float4 v = ((const float4*)src)[i];
  ushort4 o;
  o.x = bf16_bits(v.x); o.y = bf16_bits(v.y);
  o.z = bf16_bits(v.z); o.w = bf16_bits(v.w);
  ((ushort4*)dst)[i] = o;
}

// ---------------- transpose + convert: src K x N fp32 -> dst N x K bf16 ----------------
__global__ __launch_bounds__(256) void transpose_cvt(
    const float* __restrict__ src, __hip_bfloat16* __restrict__ dst, int K, int N) {
  __shared__ float T[64][65];
  const int bn = blockIdx.x * 64;
  const int bk = blockIdx.y * 64;
  const int tid = threadIdx.x;
  for (int i = tid; i < 64 * 16; i += 256) {
    int r = i >> 4, c4 = i & 15;
    float4 v = *(const float4*)&src[(size_t)(bk + r) * N + bn + c4 * 4];
    T[r][c4*4+0] = v.x; T[r][c4*4+1] = v.y; T[r][c4*4+2] = v.z; T[r][c4*4+3] = v.w;
  }
  __syncthreads();
  for (int i = tid; i < 64 * 16; i += 256) {
    int n = i >> 4, k4 = i & 15;
    ushort4 o;
    o.x = bf16_bits(T[k4*4+0][n]); o.y = bf16_bits(T[k4*4+1][n]);
    o.z = bf16_bits(T[k4*4+2][n]); o.w = bf16_bits(T[k4*4+3][n]);
    *(ushort4*)&dst[(size_t)(bn + n) * K + bk + k4 * 4] = o;
  }
}

// ---------------- bf16 MFMA GEMM (m97 structure) — kept for KV GEMM (N=2048) ----------------
__global__ __launch_bounds__(256) void gemm_mfma(
    const __hip_bfloat16* __restrict__ A, const __hip_bfloat16* __restrict__ Bt,
    void* __restrict__ C, int N, int K, int outBf16) {
  __shared__ __hip_bfloat16 As[128 * 32];
  __shared__ __hip_bfloat16 Bs[128 * 32];
  const int tid  = threadIdx.x;
  const int lane = tid & 63;
  const int wv   = tid >> 6;
  const int row0 = blockIdx.y * 128;
  const int col0 = blockIdx.x * 128;
  const int wm   = (wv & 1) * 64;
  const int wn   = (wv >> 1) * 64;
  const int lrow = lane & 15;
  const int kgrp = lane >> 4;

  f32x4 zero = {0.f, 0.f, 0.f, 0.f};
  f32x4 acc[4][4];
  #pragma unroll
  for (int mi = 0; mi < 4; ++mi)
    #pragma unroll
    for (int ni = 0; ni < 4; ++ni) acc[mi][ni] = zero;

  for (int k0 = 0; k0 < K; k0 += 32) {
    #pragma unroll
    for (int r = 0; r < 2; ++r) {
      int idx16 = r * 256 + tid;
      int arow  = idx16 >> 2;
      int akk   = (idx16 & 3) << 3;
      const __hip_bfloat16* ga = &A [(size_t)(row0 + arow) * K + k0 + akk];
      const __hip_bfloat16* gb = &Bt[(size_t)(col0 + arow) * K + k0 + akk];
      char* la = (char*)As + (r * 4096 + wv * 1024 + lane * 16);
      char* lb = (char*)Bs + (r * 4096 + wv * 1024 + lane * 16);
      __builtin_amdgcn_global_load_lds(GLB_AS(ga), LDS_AS(la), 16, 0, 0);
      __builtin_amdgcn_global_load_lds(GLB_AS(gb), LDS_AS(lb), 16, 0, 0);
    }
    __syncthreads();
    bf16x8 af[4], bfr[4];
    #pragma unroll
    for (int i = 0; i < 4; ++i) {
      af[i]  = *(const bf16x8*)&As[(wm + i * 16 + lrow) * 32 + kgrp * 8];
      bfr[i] = *(const bf16x8*)&Bs[(wn + i * 16 + lrow) * 32 + kgrp * 8];
    }
    #pragma unroll
    for (int mi = 0; mi < 4; ++mi)
      #pragma unroll
      for (int ni = 0; ni < 4; ++ni)
        acc[mi][ni] = __builtin_amdgcn_mfma_f32_16x16x32_bf16(af[mi], bfr[ni], acc[mi][ni], 0, 0, 0);
    __syncthreads();
  }

  if (outBf16) {
    __hip_bfloat16* Cb = (__hip_bfloat16*)C;
    #pragma unroll
    for (int mi = 0; mi < 4; ++mi)
      #pragma unroll
      for (int ni = 0; ni < 4; ++ni) {
        int col = col0 + wn + ni * 16 + lrow;
        int rowb = row0 + wm + mi * 16 + kgrp * 4;
        #pragma unroll
        for (int r = 0; r < 4; ++r)
          Cb[(size_t)(rowb + r) * N + col] = __float2bfloat16(acc[mi][ni][r]);
      }
  } else {
    float* Cf = (float*)C;
    #pragma unroll
    for (int mi = 0; mi < 4; ++mi)
      #pragma unroll
      for (int ni = 0; ni < 4; ++ni) {
        int col = col0 + wn + ni * 16 + lrow;
        int rowb = row0 + wm + mi * 16 + kgrp * 4;
        #pragma unroll
        for (int r = 0; r < 4; ++r)
          Cf[(size_t)(rowb + r) * N + col] = acc[mi][ni][r];
      }
  }
}

// ---------------- 256x256 8-phase bf16 MFMA GEMM (m201 template, plain HIP) ----------------
__global__ __launch_bounds__(512, 2) void gemm256(
    const __hip_bfloat16* __restrict__ A, const __hip_bfloat16* __restrict__ Bt,
    void* __restrict__ C, int N, int K, int outBf16) {
  __shared__ __hip_bfloat16 AsBuf[2][16384];   // [buf][256 rows x 64 k]
  __shared__ __hip_bfloat16 BsBuf[2][16384];

  const int tid  = threadIdx.x;
  const int lane = tid & 63;
  const int wid  = tid >> 6;
  const int wm   = wid >> 2;        // 0..1
  const int wn   = wid & 3;        // 0..3
  const int quad = lane >> 4;
  const int l15  = lane & 15;

  // XCD-aware block swizzle (bijective when nwg % 8 == 0)
  const int nbx = N >> 8;
  int bid = blockIdx.y * nbx + blockIdx.x;
  const int nwg = nbx * (int)gridDim.y;
  if ((nwg & 7) == 0) bid = (bid & 7) * (nwg >> 3) + (bid >> 3);
  const int row0 = (bid / nbx) << 8;
  const int col0 = (bid % nbx) << 8;

  const int NT = K >> 6;

  // fragment-read element offsets (swizzled): row&7 == l15&7 for all frag rows
  const int xr  = (l15 & 7) << 4;                  // byte XOR, bits 4-6
  const int ke0 = (((quad * 16)      ^ xr) >> 1);  // kc=0, elements
  const int ke1 = (((64 + quad * 16) ^ xr) >> 1);  // kc=1
  const int arE = (wm * 128 + l15) * 64;           // A row base, elements
  const int brE = (wn * 64  + l15) * 64;           // B row base, elements

  // Stage one 128-row half-tile (16 KiB): linear LDS dest, inverse-swizzled global src.
#define STG(srcp, r0g, ldsb, h, k0e) do {                                          \
    _Pragma("unroll")                                                              \
    for (int j = 0; j < 2; ++j) {                                                  \
      int p    = (j * 512 + tid) << 4;               /* byte in half-tile */       \
      int prow = p >> 7;                                                           \
      int koff = (p & 127) ^ ((prow & 7) << 4);                                    \
      const __hip_bfloat16* gsrc =                                                 \
          (srcp) + (size_t)((r0g) + (h) * 128 + prow) * K + (k0e) + (koff >> 1);   \
      char* ldst = (char*)(ldsb) + (h) * 16384 + p;                                \
      __builtin_amdgcn_global_load_lds(GLB_AS(gsrc), LDS_AS(ldst), 16, 0, 0);      \
    }                                                                              \
  } while (0)

  f32x4 acc[8][4];
  #pragma unroll
  for (int i = 0; i < 8; ++i)
    #pragma unroll
    for (int j = 0; j < 4; ++j) acc[i][j] = (f32x4){0.f, 0.f, 0.f, 0.f};

  // prologue: tile0 complete + tile1 B-halves (A-halves of tile1 come in phases 1-2 of t=0)
  STG(A,  row0, &AsBuf[0][0], 0, 0);
  STG(A,  row0, &AsBuf[0][0], 1, 0);
  STG(Bt, col0, &BsBuf[0][0], 0, 0);
  STG(Bt, col0, &BsBuf[0][0], 1, 0);
  if (NT > 1) {
    STG(Bt, col0, &BsBuf[1][0], 0, 64);
    STG(Bt, col0, &BsBuf[1][0], 1, 64);
    asm volatile("s_waitcnt vmcnt(4)" ::: "memory");   // tile0 landed, tile1 B in flight
  } else {
    asm volatile("s_waitcnt vmcnt(0)" ::: "memory");
  }
  __builtin_amdgcn_s_barrier();

  for (int t = 0; t < NT; ++t) {
    const int d  = t & 1, od = d ^ 1;
    char* Aod = (char*)&AsBuf[od][0];
    char* Bd  = (char*)&BsBuf[d][0];
    const int k1 = (t + 1) << 6, k2 = (t + 2) << 6;
    bf16x8 aH[4][2], b0[2][2], b1[2][2];

    // ---- phase 1 : Q0 = (M0, N0) ; stage A-half0(t+1) into other buf ----
    #pragma unroll
    for (int m = 0; m < 4; ++m) {
      aH[m][0] = *(const bf16x8*)&AsBuf[d][arE + m * 1024 + ke0];
      aH[m][1] = *(const bf16x8*)&AsBuf[d][arE + m * 1024 + ke1];
    }
    #pragma unroll
    for (int n = 0; n < 2; ++n) {
      b0[n][0] = *(const bf16x8*)&BsBuf[d][brE + n * 1024 + ke0];
      b0[n][1] = *(const bf16x8*)&BsBuf[d][brE + n * 1024 + ke1];
    }
    if (t + 1 < NT) STG(A, row0, Aod, 0, k1);
    __builtin_amdgcn_s_barrier();
    asm volatile("s_waitcnt lgkmcnt(0)" ::: "memory");
    __builtin_amdgcn_s_setprio(1);
    #pragma unroll
    for (int m = 0; m < 4; ++m)
      #pragma unroll
      for (int n = 0; n < 2; ++n) {
        acc[m][n] = __builtin_amdgcn_mfma_f32_16x16x32_bf16(aH[m][0], b0[n][0], acc[m][n], 0, 0, 0);
        acc[m][n] = __builtin_amdgcn_mfma_f32_16x16x32_bf16(aH[m][1], b0[n][1], acc[m][n], 0, 0, 0);
      }
    __builtin_amdgcn_s_setprio(0);
    __builtin_amdgcn_s_barrier();

    // ---- phase 2 : Q1 = (M0, N1) ; stage A-half1(t+1) ----
    #pragma unroll
    for (int n = 0; n < 2; ++n) {
      b1[n][0] = *(const bf16x8*)&BsBuf[d][brE + (n + 2) * 1024 + ke0];
      b1[n][1] = *(const bf16x8*)&BsBuf[d][brE + (n + 2) * 1024 + ke1];
    }
    if (t + 1 < NT) STG(A, row0, Aod, 1, k1);
    __builtin_amdgcn_s_barrier();
    asm volatile("s_waitcnt lgkmcnt(0)" ::: "memory");
    __builtin_amdgcn_s_setprio(1);
    #pragma unroll
    for (int m = 0; m < 4; ++m)
      #pragma unroll
      for (int n = 0; n < 2; ++n) {
        acc[m][n + 2] = __builtin_amdgcn_mfma_f32_16x16x32_bf16(aH[m][0], b1[n][0], acc[m][n + 2], 0, 0, 0);
        acc[m][n + 2] = __builtin_amdgcn_mfma_f32_16x16x32_bf16(aH[m][1], b1[n][1], acc[m][n + 2], 0, 0, 0);
      }
    __builtin_amdgcn_s_setprio(0);
    __builtin_amdgcn_s_barrier();

    // ---- phase 3 : Q2 = (M1, N1) ; stage B-half0(t+2) into own buf (B reads done @ph2) ----
    #pragma unroll
    for (int m = 0; m < 4; ++m) {
      aH[m][0] = *(const bf16x8*)&AsBuf[d][arE + 4096 + m * 1024 + ke0];
      aH[m][1] = *(const bf16x8*)&AsBuf[d][arE + 4096 + m * 1024 + ke1];
    }
    if (t + 2 < NT) STG(Bt, col0, Bd, 0, k2);
    __builtin_amdgcn_s_barrier();
    asm volatile("s_waitcnt lgkmcnt(0)" ::: "memory");
    __builtin_amdgcn_s_setprio(1);
    #pragma unroll
    for (int m = 0; m < 4; ++m)
      #pragma unroll
      for (int n = 0; n < 2; ++n) {
        acc[m + 4][n + 2] = __builtin_amdgcn_mfma_f32_16x16x32_bf16(aH[m][0], b1[n][0], acc[m + 4][n + 2], 0, 0, 0);
        acc[m + 4][n + 2] = __builtin_amdgcn_mfma_f32_16x16x32_bf16(aH[m][1], b1[n][1], acc[m + 4][n + 2], 0, 0, 0);
      }
    __builtin_amdgcn_s_setprio(0);
    __builtin_amdgcn_s_barrier();

    // ---- phase 4 : Q3 = (M1, N0) (all frags in regs) ; stage B-half1(t+2) ----
    if (t + 2 < NT) STG(Bt, col0, Bd, 1, k2);
    __builtin_amdgcn_s_barrier();
    __builtin_amdgcn_s_setprio(1);
    #pragma unroll
    for (int m = 0; m < 4; ++m)
      #pragma unroll
      for (int n = 0; n < 2; ++n) {
        acc[m + 4][n] = __builtin_amdgcn_mfma_f32_16x16x32_bf16(aH[m][0], b0[n][0], acc[m + 4][n], 0, 0, 0);
        acc[m + 4][n] = __builtin_amdgcn_mfma_f32_16x16x32_bf16(aH[m][1], b0[n][1], acc[m + 4][n], 0, 0, 0);
      }
    __builtin_amdgcn_s_setprio(0);
    // boundary: tile t+1's A-halves must be landed; keep B(t+2) (4 loads) in flight
    if (t < NT - 2)       asm volatile("s_waitcnt vmcnt(4)" ::: "memory");
    else if (t == NT - 2) asm volatile("s_waitcnt vmcnt(0)" ::: "memory");
    __builtin_amdgcn_s_barrier();
  }
#undef STG

  if (outBf16) {
    __hip_bfloat16* Cb = (__hip_bfloat16*)C;
    #pragma unroll
    for (int mi = 0; mi < 8; ++mi)
      #pragma unroll
      for (int ni = 0; ni < 4; ++ni) {
        int col  = col0 + wn * 64 + ni * 16 + l15;
        int rowb = row0 + wm * 128 + mi * 16 + quad * 4;
        #pragma unroll
        for (int r = 0; r < 4; ++r)
          Cb[(size_t)(rowb + r) * N + col] = __float2bfloat16(acc[mi][ni][r]);
      }
  } else {
    float* Cf = (float*)C;
    #pragma unroll
    for (int mi = 0; mi < 8; ++mi)
      #pragma unroll
      for (int ni = 0; ni < 4; ++ni) {
        int col  = col0 + wn * 64 + ni * 16 + l15;
        int rowb = row0 + wm * 128 + mi * 16 + quad * 4;
        #pragma unroll
        for (int r = 0; r < 4; ++r)
          Cf[(size_t)(rowb + r) * N + col] = acc[mi][ni][r];
      }
  }
}

// ---------------- RoPE on a bf16 buffer ----------------
__global__ __launch_bounds__(256) void rope_bf16(
    __hip_bfloat16* __restrict__ buf, int stride, int perRow,
    const float* __restrict__ cosb, const float* __restrict__ sinb) {
  int idx = blockIdx.x * 256 + threadIdx.x;
  int row = idx / perRow;
  if (row >= BT) return;
  int c8 = (idx - row * perRow) * 8;
  int t  = row & (TSEQ - 1);
  int cp = c8 & (DH - 1);
  __hip_bfloat16* p = buf + (size_t)row * stride + c8;
  ushort8v raw = *(const ushort8v*)p;
  const float* cr = &cosb[(size_t)t * DH + cp];
  const float* sr = &sinb[(size_t)t * DH + cp];
  ushort8v outp;
  #pragma unroll
  for (int j = 0; j < 8; j += 2) {
    float x1 = bits_f32(raw[j]), x2 = bits_f32(raw[j + 1]);
    float c = cr[j], s = sr[j];
    outp[j]     = bf16_bits(x1 * c - x2 * s);
    outp[j + 1] = bf16_bits(x1 * s + x2 * c);
  }
  *(ushort8v*)p = outp;
}

// ---------------- V transpose into dense per-(b,kvh,tile) 128x64 blobs ----------------
__global__ __launch_bounds__(256) void transpose_v(
    const __hip_bfloat16* __restrict__ kvsrc, u16* __restrict__ vt) {
  __shared__ u16 T[64][72];
  const int tid  = threadIdx.x;
  const int tile = blockIdx.x, kvh = blockIdx.y, b = blockIdx.z;
  u16* dst = vt + ((size_t)((b * NKV + kvh) * 32 + tile)) * (128 * 64);
  for (int half = 0; half < 2; ++half) {
    #pragma unroll
    for (int it = 0; it < 2; ++it) {
      int idx = it * 256 + tid;          // 512 chunks = 64 t x 8 d-chunks
      int r = idx >> 3, c8 = idx & 7;
      ushort8v vdat = *(const ushort8v*)&kvsrc[
          (size_t)(b * TSEQ + tile * 64 + r) * 2048 + 1024 + kvh * DH + half * 64 + c8 * 8];
      *(ushort8v*)&T[r][c8 * 8] = vdat;
    }
    __syncthreads();
    #pragma unroll
    for (int it = 0; it < 2; ++it) {
      int idx = it * 256 + tid;
      int d = idx >> 3, c8 = idx & 7;    // d row of output, c8: t-chunk
      ushort8v o8;
      #pragma unroll
      for (int j = 0; j < 8; ++j) o8[j] = T[c8 * 8 + j][d];
      *(ushort8v*)&dst[(size_t)(half * 64 + d) * 64 + c8 * 8] = o8;
    }
    __syncthreads();
  }
}

// ---------------- MFMA flash attention ----------------
// Round-5 measured-403us structure (T14 reg-prefetch of K AND V into LDS,
// T2 XOR-swizzle on Ks/Vs, 41.5 KB LDS) + ONE delta: LPT dispatch order.
// V-direct-from-global REVERTED (measured +46% regression: exposed L2 latency
// on the per-tile critical path; occupancy counter was a false lead).
#define PSTR 68    // Ps row stride

__global__ __launch_bounds__(256) void flash_mfma(
    const __hip_bfloat16* __restrict__ q,    // (BT, 4096)
    const __hip_bfloat16* __restrict__ kv,   // kvb (BT, 2048); k at col kvh*128
    const u16* __restrict__ vt,              // V^T blobs
    __hip_bfloat16* __restrict__ o,          // (BT, 4096)
    const int* __restrict__ causal_p) {
  __shared__ u16 Ks[64 * 128];      // [kv][d], swizzled
  __shared__ u16 Vs[128 * 64];      // [d][kv], swizzled
  __shared__ u16 Ps[4][16 * PSTR];  // per-wave [q][kv]

  const int tid  = threadIdx.x;
  const int lane = tid & 63;
  const int wq   = tid >> 6;
  const int quad = lane >> 4;
  const int l15  = lane & 15;
  const int mtile = (int)gridDim.x - 1 - (int)blockIdx.x;   // LPT order (the single delta)
  const int h = blockIdx.y, b = blockIdx.z;
  const int kvh = h >> 2;
  const int m0  = mtile * 64;
  const bool causal = (*causal_p != 0);
  const float NEG_INF = -__builtin_inff();
  const float scale = 0.08838834764831845f;
  const int swz = (l15 & 7) << 3;   // element XOR for this lane's LDS reads

  bf16x8 qf[4];
  {
    const __hip_bfloat16* qrow =
        &q[(size_t)(b * TSEQ + m0 + wq * 16 + l15) * CDIM + h * DH + quad * 8];
    #pragma unroll
    for (int kc = 0; kc < 4; ++kc) qf[kc] = *(const bf16x8*)(qrow + kc * 32);
  }

  f32x4 Ot[8];
  #pragma unroll
  for (int dt = 0; dt < 8; ++dt) Ot[dt] = (f32x4){0.f, 0.f, 0.f, 0.f};
  float mrow[4] = {NEG_INF, NEG_INF, NEG_INF, NEG_INF};
  float lrow[4] = {0.f, 0.f, 0.f, 0.f};

  const int ntiles = causal ? (mtile + 1) : (TSEQ / 64);
  u16* Pw = &Ps[wq][0];
  const u16* vtbase = vt + ((size_t)(b * NKV + kvh) * 32) * (128 * 64);

  ushort8v kreg[4], vreg[4];
  // prologue: stage tile 0
  #pragma unroll
  for (int it = 0; it < 4; ++it) {
    int idx = it * 256 + tid;
    int r = idx >> 4, c8 = idx & 15;
    kreg[it] = *(const ushort8v*)&kv[(size_t)(b * TSEQ + r) * 2048 + kvh * DH + c8 * 8];
    int d = idx >> 3, c8v = idx & 7;
    vreg[it] = *(const ushort8v*)&vtbase[(size_t)d * 64 + c8v * 8];
  }
  #pragma unroll
  for (int it = 0; it < 4; ++it) {
    int idx = it * 256 + tid;
    int r = idx >> 4, c8 = idx & 15;
    *(ushort8v*)&Ks[r * 128 + ((c8 ^ (r & 7)) * 8)] = kreg[it];
    int d = idx >> 3, c8v = idx & 7;
    *(ushort8v*)&Vs[d * 64 + ((c8v ^ (d & 7)) * 8)] = vreg[it];
  }
  __syncthreads();

  for (int tile = 0; tile < ntiles; ++tile) {
    const int j0 = tile * 64;
    // prefetch next K/V tile into registers (latency hides under compute)
    if (tile + 1 < ntiles) {
      const u16* vblob = vtbase + (size_t)(tile + 1) * (128 * 64);
      #pragma unroll
      for (int it = 0; it < 4; ++it) {
        int idx = it * 256 + tid;
        int r = idx >> 4, c8 = idx & 15;
        kreg[it] = *(const ushort8v*)&kv[(size_t)(b * TSEQ + j0 + 64 + r) * 2048 + kvh * DH + c8 * 8];
        int d = idx >> 3, c8v = idx & 7;
        vreg[it] = *(const ushort8v*)&vblob[(size_t)d * 64 + c8v * 8];
      }
    }

    // S = Q K^T : 4 kv 16-tiles x 4 d-chunks
    f32x4 S[4];
    #pragma unroll
    for (int jt = 0; jt < 4; ++jt) {
      f32x4 acc = {0.f, 0.f, 0.f, 0.f};
      #pragma unroll
      for (int kc = 0; kc < 4; ++kc) {
        bf16x8 kf = *(const bf16x8*)&Ks[(jt * 16 + l15) * 128 + ((kc * 32 + quad * 8) ^ swz)];
        acc = __builtin_amdgcn_mfma_f32_16x16x32_bf16(qf[kc], kf, acc, 0, 0, 0);
      }
      S[jt] = acc;
    }
    #pragma unroll
    for (int jt = 0; jt < 4; ++jt)
      #pragma unroll
      for (int r = 0; r < 4; ++r) S[jt][r] *= scale;
    if (causal && tile == mtile) {
      const int qr0 = m0 + wq * 16 + quad * 4;
      #pragma unroll
      for (int jt = 0; jt < 4; ++jt)
        #pragma unroll
        for (int r = 0; r < 4; ++r)
          if (j0 + jt * 16 + l15 > qr0 + r) S[jt][r] = NEG_INF;
    }

    // online softmax: rows = quad*4+r, cols across 16 lanes of the quad group
    float alpha[4], rsum[4];
    #pragma unroll
    for (int r = 0; r < 4; ++r) {
      float mx = fmaxf(fmaxf(S[0][r], S[1][r]), fmaxf(S[2][r], S[3][r]));
      #pragma unroll
      for (int w = 1; w <= 8; w <<= 1) mx = fmaxf(mx, __shfl_xor(mx, w));
      float mn = fmaxf(mrow[r], mx);
      alpha[r] = __expf(mrow[r] - mn);
      mrow[r] = mn;
      rsum[r] = 0.f;
    }
    #pragma unroll
    for (int jt = 0; jt < 4; ++jt)
      #pragma unroll
      for (int r = 0; r < 4; ++r) {
        float p = __expf(S[jt][r] - mrow[r]);   // masked -> exp(-inf) = 0
        rsum[r] += p;
        Pw[(quad * 4 + r) * PSTR + jt * 16 + l15] = bf16_bits(p);
      }
    #pragma unroll
    for (int r = 0; r < 4; ++r) {
      float s = rsum[r];
      #pragma unroll
      for (int w = 1; w <= 8; w <<= 1) s += __shfl_xor(s, w);
      lrow[r] = lrow[r] * alpha[r] + s;
    }
    // rescale O
    #pragma unroll
    for (int dt = 0; dt < 8; ++dt)
      #pragma unroll
      for (int r = 0; r < 4; ++r) Ot[dt][r] *= alpha[r];

    // O += P V : A = P[m=q][k=kv], B = V[n=d][k=kv]
    #pragma unroll
    for (int kc = 0; kc < 2; ++kc) {
      bf16x8 pf = *(const bf16x8*)&Pw[l15 * PSTR + kc * 32 + quad * 8];
      #pragma unroll
      for (int dt = 0; dt < 8; ++dt) {
        bf16x8 vf = *(const bf16x8*)&Vs[(dt * 16 + l15) * 64 + ((kc * 32 + quad * 8) ^ swz)];
        Ot[dt] = __builtin_amdgcn_mfma_f32_16x16x32_bf16(pf, vf, Ot[dt], 0, 0, 0);
      }
    }

    // write next tile to LDS after all waves finished reading this one
    if (tile + 1 < ntiles) {
      __syncthreads();
      #pragma unroll
      for (int it = 0; it < 4; ++it) {
        int idx = it * 256 + tid;
        int r = idx >> 4, c8 = idx & 15;
        *(ushort8v*)&Ks[r * 128 + ((c8 ^ (r & 7)) * 8)] = kreg[it];
        int d = idx >> 3, c8v = idx & 7;
        *(ushort8v*)&Vs[d * 64 + ((c8v ^ (d & 7)) * 8)] = vreg[it];
      }
      __syncthreads();
    }
  }

  // epilogue: normalize and store
  float invl[4];
  #pragma unroll
  for (int r = 0; r < 4; ++r) invl[r] = 1.f / lrow[r];
  #pragma unroll
  for (int dt = 0; dt < 8; ++dt)
    #pragma unroll
    for (int r = 0; r < 4; ++r)
      o[(size_t)(b * TSEQ + m0 + wq * 16 + quad * 4 + r) * CDIM + h * DH + dt * 16 + l15] =
          __float2bfloat16(Ot[dt][r] * invl[r]);
}

// ---------------- launch ----------------
extern "C" void kernel_launch(void* const* d_in, const int* in_sizes, int n_in,
                              void* d_out, int out_size, void* d_ws, size_t ws_size,
                              hipStream_t stream) {
  const float* x    = (const float*)d_in[0];
  const float* wq   = (const float*)d_in[1];
  const float* wk   = (const float*)d_in[2];
  const float* wv   = (const float*)d_in[3];
  const float* wo   = (const float*)d_in[4];
  const float* cosb = (const float*)d_in[5];
  const float* sinb = (const float*)d_in[6];
  const int* causal = (const int*)d_in[7];

  char* wsb = (char*)d_ws;
  __hip_bfloat16* xb   = (__hip_bfloat16*)(wsb);
  __hip_bfloat16* woT  = (__hip_bfloat16*)(wsb);
  __hip_bfloat16* wqT  = (__hip_bfloat16*)(wsb + (((size_t)32) << 20));
  __hip_bfloat16* obuf = (__hip_bfloat16*)(wsb + (((size_t)32) << 20));
  __hip_bfloat16* wkvT = (__hip_bfloat16*)(wsb + (((size_t)64) << 20));
  u16*            vtb  = (u16*)           (wsb + (((size_t)64) << 20));
  __hip_bfloat16* kvb  = (__hip_bfloat16*)(wsb + (((size_t)80) << 20));
  __hip_bfloat16* qb   = (__hip_bfloat16*)d_out;

  dim3 blk(256);
  dim3 blk5(512);
  cvt_bf16x4<<<dim3((BT * CDIM / 4 + 255) / 256), blk, 0, stream>>>(x, xb, BT * CDIM / 4);
  transpose_cvt<<<dim3(CDIM / 64, CDIM / 64), blk, 0, stream>>>(wq, wqT, CDIM, CDIM);
  transpose_cvt<<<dim3(1024 / 64, CDIM / 64), blk, 0, stream>>>(wk, wkvT, CDIM, 1024);
  transpose_cvt<<<dim3(1024 / 64, CDIM / 64), blk, 0, stream>>>(wv, wkvT + (size_t)1024 * CDIM, CDIM, 1024);
  gemm256<<<dim3(CDIM / 256, BT / 256), blk5, 0, stream>>>(xb, wqT, qb, CDIM, CDIM, 1);
  gemm_mfma<<<dim3(2048 / 128, BT / 128), blk, 0, stream>>>(xb, wkvT, kvb, 2048, CDIM, 1);
  transpose_v<<<dim3(32, NKV, BSZ), blk, 0, stream>>>(kvb, vtb);
  rope_bf16<<<dim3(BT * (CDIM / 8) / 256), blk, 0, stream>>>(qb, CDIM, CDIM / 8, cosb, sinb);
  rope_bf16<<<dim3(BT * (1024 / 8) / 256), blk, 0, stream>>>(kvb, 2048, 1024 / 8, cosb, sinb);
  transpose_cvt<<<dim3(CDIM / 64, CDIM / 64), blk, 0, stream>>>(wo, woT, CDIM, CDIM);
  flash_mfma<<<dim3(TSEQ / 64, NH, BSZ), blk, 0, stream>>>(qb, kvb, vtb, obuf, causal);
  gemm256<<<dim3(CDIM / 256, BT / 256), blk5, 0, stream>>>(obuf, woT, d_out, CDIM, CDIM, 0);
}

// Round 14
// 935.856 us; speedup vs baseline: 1.2745x; 1.0821x over previous
//
#include <hip/hip_runtime.h>
#include <hip/hip_bf16.h>

// Problem constants
#define BSZ   2
#define TSEQ  2048
#define CDIM  4096
#define NH    32
#define NKV   8
#define GQ    4
#define DH    128
#define BT    (BSZ * TSEQ)   // 4096

typedef short   bf16x8  __attribute__((ext_vector_type(8)));
typedef float   f32x4   __attribute__((ext_vector_type(4)));
typedef unsigned short ushort8v __attribute__((ext_vector_type(8)));
typedef unsigned short u16;

#define LDS_AS(p) ((__attribute__((address_space(3))) void*)(p))
#define GLB_AS(p) ((const __attribute__((address_space(1))) void*)(p))

static __device__ inline unsigned short bf16_bits(float f) {
  __hip_bfloat16 h = __float2bfloat16(f);
  return *(unsigned short*)&h;
}
static __device__ inline float bits_f32(unsigned short u) {
  unsigned v = ((unsigned)u) << 16;
  return __builtin_bit_cast(float, v);
}

// ---------------- fp32 -> bf16 elementwise ----------------
__global__ __launch_bounds__(256) void cvt_bf16x4(
    const float* __restrict__ src, __hip_bfloat16* __restrict__ dst, int n4) {
  int i = blockIdx.x * 256 + threadIdx.x;
  if (i >= n4) return;
  float4 v = ((const float4*)src)[i];
  ushort4 o;
  o.x = bf16_bits(v.x); o.y = bf16_bits(v.y);
  o.z = bf16_bits(v.z); o.w = bf16_bits(v.w);
  ((ushort4*)dst)[i] = o;
}

// ---------------- transpose + convert: src K x N fp32 -> dst N x K bf16 ----------------
__global__ __launch_bounds__(256) void transpose_cvt(
    const float* __restrict__ src, __hip_bfloat16* __restrict__ dst, int K, int N) {
  __shared__ float T[64][65];
  const int bn = blockIdx.x * 64;
  const int bk = blockIdx.y * 64;
  const int tid = threadIdx.x;
  for (int i = tid; i < 64 * 16; i += 256) {
    int r = i >> 4, c4 = i & 15;
    float4 v = *(const float4*)&src[(size_t)(bk + r) * N + bn + c4 * 4];
    T[r][c4*4+0] = v.x; T[r][c4*4+1] = v.y; T[r][c4*4+2] = v.z; T[r][c4*4+3] = v.w;
  }
  __syncthreads();
  for (int i = tid; i < 64 * 16; i += 256) {
    int n = i >> 4, k4 = i & 15;
    ushort4 o;
    o.x = bf16_bits(T[k4*4+0][n]); o.y = bf16_bits(T[k4*4+1][n]);
    o.z = bf16_bits(T[k4*4+2][n]); o.w = bf16_bits(T[k4*4+3][n]);
    *(ushort4*)&dst[(size_t)(bn + n) * K + bk + k4 * 4] = o;
  }
}

// ---------------- bf16 MFMA GEMM (m97 structure) — kept for KV GEMM (N=2048) ----------------
__global__ __launch_bounds__(256) void gemm_mfma(
    const __hip_bfloat16* __restrict__ A, const __hip_bfloat16* __restrict__ Bt,
    void* __restrict__ C, int N, int K, int outBf16) {
  __shared__ __hip_bfloat16 As[128 * 32];
  __shared__ __hip_bfloat16 Bs[128 * 32];
  const int tid  = threadIdx.x;
  const int lane = tid & 63;
  const int wv   = tid >> 6;
  const int row0 = blockIdx.y * 128;
  const int col0 = blockIdx.x * 128;
  const int wm   = (wv & 1) * 64;
  const int wn   = (wv >> 1) * 64;
  const int lrow = lane & 15;
  const int kgrp = lane >> 4;

  f32x4 zero = {0.f, 0.f, 0.f, 0.f};
  f32x4 acc[4][4];
  #pragma unroll
  for (int mi = 0; mi < 4; ++mi)
    #pragma unroll
    for (int ni = 0; ni < 4; ++ni) acc[mi][ni] = zero;

  for (int k0 = 0; k0 < K; k0 += 32) {
    #pragma unroll
    for (int r = 0; r < 2; ++r) {
      int idx16 = r * 256 + tid;
      int arow  = idx16 >> 2;
      int akk   = (idx16 & 3) << 3;
      const __hip_bfloat16* ga = &A [(size_t)(row0 + arow) * K + k0 + akk];
      const __hip_bfloat16* gb = &Bt[(size_t)(col0 + arow) * K + k0 + akk];
      char* la = (char*)As + (r * 4096 + wv * 1024 + lane * 16);
      char* lb = (char*)Bs + (r * 4096 + wv * 1024 + lane * 16);
      __builtin_amdgcn_global_load_lds(GLB_AS(ga), LDS_AS(la), 16, 0, 0);
      __builtin_amdgcn_global_load_lds(GLB_AS(gb), LDS_AS(lb), 16, 0, 0);
    }
    __syncthreads();
    bf16x8 af[4], bfr[4];
    #pragma unroll
    for (int i = 0; i < 4; ++i) {
      af[i]  = *(const bf16x8*)&As[(wm + i * 16 + lrow) * 32 + kgrp * 8];
      bfr[i] = *(const bf16x8*)&Bs[(wn + i * 16 + lrow) * 32 + kgrp * 8];
    }
    #pragma unroll
    for (int mi = 0; mi < 4; ++mi)
      #pragma unroll
      for (int ni = 0; ni < 4; ++ni)
        acc[mi][ni] = __builtin_amdgcn_mfma_f32_16x16x32_bf16(af[mi], bfr[ni], acc[mi][ni], 0, 0, 0);
    __syncthreads();
  }

  if (outBf16) {
    __hip_bfloat16* Cb = (__hip_bfloat16*)C;
    #pragma unroll
    for (int mi = 0; mi < 4; ++mi)
      #pragma unroll
      for (int ni = 0; ni < 4; ++ni) {
        int col = col0 + wn + ni * 16 + lrow;
        int rowb = row0 + wm + mi * 16 + kgrp * 4;
        #pragma unroll
        for (int r = 0; r < 4; ++r)
          Cb[(size_t)(rowb + r) * N + col] = __float2bfloat16(acc[mi][ni][r]);
      }
  } else {
    float* Cf = (float*)C;
    #pragma unroll
    for (int mi = 0; mi < 4; ++mi)
      #pragma unroll
      for (int ni = 0; ni < 4; ++ni) {
        int col = col0 + wn + ni * 16 + lrow;
        int rowb = row0 + wm + mi * 16 + kgrp * 4;
        #pragma unroll
        for (int r = 0; r < 4; ++r)
          Cf[(size_t)(rowb + r) * N + col] = acc[mi][ni][r];
      }
  }
}

// ---------------- 256x256 8-phase bf16 MFMA GEMM (m201 template, plain HIP) ----------------
__global__ __launch_bounds__(512, 2) void gemm256(
    const __hip_bfloat16* __restrict__ A, const __hip_bfloat16* __restrict__ Bt,
    void* __restrict__ C, int N, int K, int outBf16) {
  __shared__ __hip_bfloat16 AsBuf[2][16384];   // [buf][256 rows x 64 k]
  __shared__ __hip_bfloat16 BsBuf[2][16384];

  const int tid  = threadIdx.x;
  const int lane = tid & 63;
  const int wid  = tid >> 6;
  const int wm   = wid >> 2;        // 0..1
  const int wn   = wid & 3;         // 0..3
  const int quad = lane >> 4;
  const int l15  = lane & 15;

  // XCD-aware block swizzle (bijective when nwg % 8 == 0)
  const int nbx = N >> 8;
  int bid = blockIdx.y * nbx + blockIdx.x;
  const int nwg = nbx * (int)gridDim.y;
  if ((nwg & 7) == 0) bid = (bid & 7) * (nwg >> 3) + (bid >> 3);
  const int row0 = (bid / nbx) << 8;
  const int col0 = (bid % nbx) << 8;

  const int NT = K >> 6;

  // fragment-read element offsets (swizzled): row&7 == l15&7 for all frag rows
  const int xr  = (l15 & 7) << 4;                  // byte XOR, bits 4-6
  const int ke0 = (((quad * 16)      ^ xr) >> 1);  // kc=0, elements
  const int ke1 = (((64 + quad * 16) ^ xr) >> 1);  // kc=1
  const int arE = (wm * 128 + l15) * 64;           // A row base, elements
  const int brE = (wn * 64  + l15) * 64;           // B row base, elements

  // Stage one 128-row half-tile (16 KiB): linear LDS dest, inverse-swizzled global src.
#define STG(srcp, r0g, ldsb, h, k0e) do {                                          \
    _Pragma("unroll")                                                              \
    for (int j = 0; j < 2; ++j) {                                                  \
      int p    = (j * 512 + tid) << 4;               /* byte in half-tile */       \
      int prow = p >> 7;                                                           \
      int koff = (p & 127) ^ ((prow & 7) << 4);                                    \
      const __hip_bfloat16* gsrc =                                                 \
          (srcp) + (size_t)((r0g) + (h) * 128 + prow) * K + (k0e) + (koff >> 1);   \
      char* ldst = (char*)(ldsb) + (h) * 16384 + p;                                \
      __builtin_amdgcn_global_load_lds(GLB_AS(gsrc), LDS_AS(ldst), 16, 0, 0);      \
    }                                                                              \
  } while (0)

  f32x4 acc[8][4];
  #pragma unroll
  for (int i = 0; i < 8; ++i)
    #pragma unroll
    for (int j = 0; j < 4; ++j) acc[i][j] = (f32x4){0.f, 0.f, 0.f, 0.f};

  // prologue: tile0 complete + tile1 B-halves (A-halves of tile1 come in phases 1-2 of t=0)
  STG(A,  row0, &AsBuf[0][0], 0, 0);
  STG(A,  row0, &AsBuf[0][0], 1, 0);
  STG(Bt, col0, &BsBuf[0][0], 0, 0);
  STG(Bt, col0, &BsBuf[0][0], 1, 0);
  if (NT > 1) {
    STG(Bt, col0, &BsBuf[1][0], 0, 64);
    STG(Bt, col0, &BsBuf[1][0], 1, 64);
    asm volatile("s_waitcnt vmcnt(4)" ::: "memory");   // tile0 landed, tile1 B in flight
  } else {
    asm volatile("s_waitcnt vmcnt(0)" ::: "memory");
  }
  __builtin_amdgcn_s_barrier();

  for (int t = 0; t < NT; ++t) {
    const int d  = t & 1, od = d ^ 1;
    char* Aod = (char*)&AsBuf[od][0];
    char* Bd  = (char*)&BsBuf[d][0];
    const int k1 = (t + 1) << 6, k2 = (t + 2) << 6;
    bf16x8 aH[4][2], b0[2][2], b1[2][2];

    // ---- phase 1 : Q0 = (M0, N0) ; stage A-half0(t+1) into other buf ----
    #pragma unroll
    for (int m = 0; m < 4; ++m) {
      aH[m][0] = *(const bf16x8*)&AsBuf[d][arE + m * 1024 + ke0];
      aH[m][1] = *(const bf16x8*)&AsBuf[d][arE + m * 1024 + ke1];
    }
    #pragma unroll
    for (int n = 0; n < 2; ++n) {
      b0[n][0] = *(const bf16x8*)&BsBuf[d][brE + n * 1024 + ke0];
      b0[n][1] = *(const bf16x8*)&BsBuf[d][brE + n * 1024 + ke1];
    }
    if (t + 1 < NT) STG(A, row0, Aod, 0, k1);
    __builtin_amdgcn_s_barrier();
    asm volatile("s_waitcnt lgkmcnt(0)" ::: "memory");
    __builtin_amdgcn_s_setprio(1);
    #pragma unroll
    for (int m = 0; m < 4; ++m)
      #pragma unroll
      for (int n = 0; n < 2; ++n) {
        acc[m][n] = __builtin_amdgcn_mfma_f32_16x16x32_bf16(aH[m][0], b0[n][0], acc[m][n], 0, 0, 0);
        acc[m][n] = __builtin_amdgcn_mfma_f32_16x16x32_bf16(aH[m][1], b0[n][1], acc[m][n], 0, 0, 0);
      }
    __builtin_amdgcn_s_setprio(0);
    __builtin_amdgcn_s_barrier();

    // ---- phase 2 : Q1 = (M0, N1) ; stage A-half1(t+1) ----
    #pragma unroll
    for (int n = 0; n < 2; ++n) {
      b1[n][0] = *(const bf16x8*)&BsBuf[d][brE + (n + 2) * 1024 + ke0];
      b1[n][1] = *(const bf16x8*)&BsBuf[d][brE + (n + 2) * 1024 + ke1];
    }
    if (t + 1 < NT) STG(A, row0, Aod, 1, k1);
    __builtin_amdgcn_s_barrier();
    asm volatile("s_waitcnt lgkmcnt(0)" ::: "memory");
    __builtin_amdgcn_s_setprio(1);
    #pragma unroll
    for (int m = 0; m < 4; ++m)
      #pragma unroll
      for (int n = 0; n < 2; ++n) {
        acc[m][n + 2] = __builtin_amdgcn_mfma_f32_16x16x32_bf16(aH[m][0], b1[n][0], acc[m][n + 2], 0, 0, 0);
        acc[m][n + 2] = __builtin_amdgcn_mfma_f32_16x16x32_bf16(aH[m][1], b1[n][1], acc[m][n + 2], 0, 0, 0);
      }
    __builtin_amdgcn_s_setprio(0);
    __builtin_amdgcn_s_barrier();

    // ---- phase 3 : Q2 = (M1, N1) ; stage B-half0(t+2) into own buf (B reads done @ph2) ----
    #pragma unroll
    for (int m = 0; m < 4; ++m) {
      aH[m][0] = *(const bf16x8*)&AsBuf[d][arE + 4096 + m * 1024 + ke0];
      aH[m][1] = *(const bf16x8*)&AsBuf[d][arE + 4096 + m * 1024 + ke1];
    }
    if (t + 2 < NT) STG(Bt, col0, Bd, 0, k2);
    __builtin_amdgcn_s_barrier();
    asm volatile("s_waitcnt lgkmcnt(0)" ::: "memory");
    __builtin_amdgcn_s_setprio(1);
    #pragma unroll
    for (int m = 0; m < 4; ++m)
      #pragma unroll
      for (int n = 0; n < 2; ++n) {
        acc[m + 4][n + 2] = __builtin_amdgcn_mfma_f32_16x16x32_bf16(aH[m][0], b1[n][0], acc[m + 4][n + 2], 0, 0, 0);
        acc[m + 4][n + 2] = __builtin_amdgcn_mfma_f32_16x16x32_bf16(aH[m][1], b1[n][1], acc[m + 4][n + 2], 0, 0, 0);
      }
    __builtin_amdgcn_s_setprio(0);
    __builtin_amdgcn_s_barrier();

    // ---- phase 4 : Q3 = (M1, N0) (all frags in regs) ; stage B-half1(t+2) ----
    if (t + 2 < NT) STG(Bt, col0, Bd, 1, k2);
    __builtin_amdgcn_s_barrier();
    __builtin_amdgcn_s_setprio(1);
    #pragma unroll
    for (int m = 0; m < 4; ++m)
      #pragma unroll
      for (int n = 0; n < 2; ++n) {
        acc[m + 4][n] = __builtin_amdgcn_mfma_f32_16x16x32_bf16(aH[m][0], b0[n][0], acc[m + 4][n], 0, 0, 0);
        acc[m + 4][n] = __builtin_amdgcn_mfma_f32_16x16x32_bf16(aH[m][1], b0[n][1], acc[m + 4][n], 0, 0, 0);
      }
    __builtin_amdgcn_s_setprio(0);
    // boundary: tile t+1's A-halves must be landed; keep B(t+2) (4 loads) in flight
    if (t < NT - 2)       asm volatile("s_waitcnt vmcnt(4)" ::: "memory");
    else if (t == NT - 2) asm volatile("s_waitcnt vmcnt(0)" ::: "memory");
    __builtin_amdgcn_s_barrier();
  }
#undef STG

  if (outBf16) {
    __hip_bfloat16* Cb = (__hip_bfloat16*)C;
    #pragma unroll
    for (int mi = 0; mi < 8; ++mi)
      #pragma unroll
      for (int ni = 0; ni < 4; ++ni) {
        int col  = col0 + wn * 64 + ni * 16 + l15;
        int rowb = row0 + wm * 128 + mi * 16 + quad * 4;
        #pragma unroll
        for (int r = 0; r < 4; ++r)
          Cb[(size_t)(rowb + r) * N + col] = __float2bfloat16(acc[mi][ni][r]);
      }
  } else {
    float* Cf = (float*)C;
    #pragma unroll
    for (int mi = 0; mi < 8; ++mi)
      #pragma unroll
      for (int ni = 0; ni < 4; ++ni) {
        int col  = col0 + wn * 64 + ni * 16 + l15;
        int rowb = row0 + wm * 128 + mi * 16 + quad * 4;
        #pragma unroll
        for (int r = 0; r < 4; ++r)
          Cf[(size_t)(rowb + r) * N + col] = acc[mi][ni][r];
      }
  }
}

// ---------------- RoPE on a bf16 buffer ----------------
__global__ __launch_bounds__(256) void rope_bf16(
    __hip_bfloat16* __restrict__ buf, int stride, int perRow,
    const float* __restrict__ cosb, const float* __restrict__ sinb) {
  int idx = blockIdx.x * 256 + threadIdx.x;
  int row = idx / perRow;
  if (row >= BT) return;
  int c8 = (idx - row * perRow) * 8;
  int t  = row & (TSEQ - 1);
  int cp = c8 & (DH - 1);
  __hip_bfloat16* p = buf + (size_t)row * stride + c8;
  ushort8v raw = *(const ushort8v*)p;
  const float* cr = &cosb[(size_t)t * DH + cp];
  const float* sr = &sinb[(size_t)t * DH + cp];
  ushort8v outp;
  #pragma unroll
  for (int j = 0; j < 8; j += 2) {
    float x1 = bits_f32(raw[j]), x2 = bits_f32(raw[j + 1]);
    float c = cr[j], s = sr[j];
    outp[j]     = bf16_bits(x1 * c - x2 * s);
    outp[j + 1] = bf16_bits(x1 * s + x2 * c);
  }
  *(ushort8v*)p = outp;
}

// ---------------- V transpose into dense per-(b,kvh,tile) 128x64 blobs ----------------
__global__ __launch_bounds__(256) void transpose_v(
    const __hip_bfloat16* __restrict__ kvsrc, u16* __restrict__ vt) {
  __shared__ u16 T[64][72];
  const int tid  = threadIdx.x;
  const int tile = blockIdx.x, kvh = blockIdx.y, b = blockIdx.z;
  u16* dst = vt + ((size_t)((b * NKV + kvh) * 32 + tile)) * (128 * 64);
  for (int half = 0; half < 2; ++half) {
    #pragma unroll
    for (int it = 0; it < 2; ++it) {
      int idx = it * 256 + tid;          // 512 chunks = 64 t x 8 d-chunks
      int r = idx >> 3, c8 = idx & 7;
      ushort8v vdat = *(const ushort8v*)&kvsrc[
          (size_t)(b * TSEQ + tile * 64 + r) * 2048 + 1024 + kvh * DH + half * 64 + c8 * 8];
      *(ushort8v*)&T[r][c8 * 8] = vdat;
    }
    __syncthreads();
    #pragma unroll
    for (int it = 0; it < 2; ++it) {
      int idx = it * 256 + tid;
      int d = idx >> 3, c8 = idx & 7;    // d row of output, c8: t-chunk
      ushort8v o8;
      #pragma unroll
      for (int j = 0; j < 8; ++j) o8[j] = T[c8 * 8 + j][d];
      *(ushort8v*)&dst[(size_t)(half * 64 + d) * 64 + c8 * 8] = o8;
    }
    __syncthreads();
  }
}

// ---------------- MFMA flash attention ----------------
// 8-wave QBLK=128 version of the measured-403us structure: same per-wave code,
// K/V staging + barriers amortized over 2x q-rows; 512 thr; LDS ~49 KB
// (3 blocks/CU = 24 waves). Causal: ntiles = 2*mtile+2; waves past their
// diagonal skip compute (wave-uniform branch, barriers outside).
#define PSTR 68    // Ps row stride

__global__ __launch_bounds__(512, 4) void flash_mfma(
    const __hip_bfloat16* __restrict__ q,    // (BT, 4096)
    const __hip_bfloat16* __restrict__ kv,   // kvb (BT, 2048); k at col kvh*128
    const u16* __restrict__ vt,              // V^T blobs
    __hip_bfloat16* __restrict__ o,          // (BT, 4096)
    const int* __restrict__ causal_p) {
  __shared__ u16 Ks[64 * 128];      // [kv][d], swizzled
  __shared__ u16 Vs[128 * 64];      // [d][kv], swizzled
  __shared__ u16 Ps[8][16 * PSTR];  // per-wave [q][kv]

  const int tid  = threadIdx.x;
  const int lane = tid & 63;
  const int wq   = tid >> 6;        // 0..7
  const int quad = lane >> 4;
  const int l15  = lane & 15;
  const int mtile = (int)gridDim.x - 1 - (int)blockIdx.x;   // LPT order
  const int h = blockIdx.y, b = blockIdx.z;
  const int kvh = h >> 2;
  const int m0  = mtile * 128;
  const bool causal = (*causal_p != 0);
  const float NEG_INF = -__builtin_inff();
  const float scale = 0.08838834764831845f;
  const int swz = (l15 & 7) << 3;   // element XOR for this lane's LDS reads
  const int qr0 = m0 + wq * 16 + quad * 4;   // this thread's first q row
  const int qrMax = m0 + wq * 16 + 15;       // wave's last q row

  bf16x8 qf[4];
  {
    const __hip_bfloat16* qrow =
        &q[(size_t)(b * TSEQ + m0 + wq * 16 + l15) * CDIM + h * DH + quad * 8];
    #pragma unroll
    for (int kc = 0; kc < 4; ++kc) qf[kc] = *(const bf16x8*)(qrow + kc * 32);
  }

  f32x4 Ot[8];
  #pragma unroll
  for (int dt = 0; dt < 8; ++dt) Ot[dt] = (f32x4){0.f, 0.f, 0.f, 0.f};
  float mrow[4] = {NEG_INF, NEG_INF, NEG_INF, NEG_INF};
  float lrow[4] = {0.f, 0.f, 0.f, 0.f};

  const int ntiles = causal ? (2 * mtile + 2) : (TSEQ / 64);
  u16* Pw = &Ps[wq][0];
  const u16* vtbase = vt + ((size_t)(b * NKV + kvh) * 32) * (128 * 64);

  ushort8v kreg[2], vreg[2];
  // prologue: stage K/V tile 0 (1024 chunks each, 512 threads, 2 iters)
  #pragma unroll
  for (int it = 0; it < 2; ++it) {
    int idx = it * 512 + tid;
    int r = idx >> 4, c8 = idx & 15;
    kreg[it] = *(const ushort8v*)&kv[(size_t)(b * TSEQ + r) * 2048 + kvh * DH + c8 * 8];
    int d = idx >> 3, c8v = idx & 7;
    vreg[it] = *(const ushort8v*)&vtbase[(size_t)d * 64 + c8v * 8];
  }
  #pragma unroll
  for (int it = 0; it < 2; ++it) {
    int idx = it * 512 + tid;
    int r = idx >> 4, c8 = idx & 15;
    *(ushort8v*)&Ks[r * 128 + ((c8 ^ (r & 7)) * 8)] = kreg[it];
    int d = idx >> 3, c8v = idx & 7;
    *(ushort8v*)&Vs[d * 64 + ((c8v ^ (d & 7)) * 8)] = vreg[it];
  }
  __syncthreads();

  for (int tile = 0; tile < ntiles; ++tile) {
    const int j0 = tile * 64;
    // prefetch next K/V tile into registers (latency hides under compute)
    if (tile + 1 < ntiles) {
      const u16* vblob = vtbase + (size_t)(tile + 1) * (128 * 64);
      #pragma unroll
      for (int it = 0; it < 2; ++it) {
        int idx = it * 512 + tid;
        int r = idx >> 4, c8 = idx & 15;
        kreg[it] = *(const ushort8v*)&kv[(size_t)(b * TSEQ + j0 + 64 + r) * 2048 + kvh * DH + c8 * 8];
        int d = idx >> 3, c8v = idx & 7;
        vreg[it] = *(const ushort8v*)&vblob[(size_t)d * 64 + c8v * 8];
      }
    }

    // waves whose q-rows all precede this kv tile skip compute (wave-uniform)
    const bool active = !causal || (j0 <= qrMax);
    if (active) {
      // S = Q K^T : 4 kv 16-tiles x 4 d-chunks
      f32x4 S[4];
      #pragma unroll
      for (int jt = 0; jt < 4; ++jt) {
        f32x4 acc = {0.f, 0.f, 0.f, 0.f};
        #pragma unroll
        for (int kc = 0; kc < 4; ++kc) {
          bf16x8 kf = *(const bf16x8*)&Ks[(jt * 16 + l15) * 128 + ((kc * 32 + quad * 8) ^ swz)];
          acc = __builtin_amdgcn_mfma_f32_16x16x32_bf16(qf[kc], kf, acc, 0, 0, 0);
        }
        S[jt] = acc;
      }
      #pragma unroll
      for (int jt = 0; jt < 4; ++jt)
        #pragma unroll
        for (int r = 0; r < 4; ++r) S[jt][r] *= scale;
      if (causal && (j0 + 63 > m0 + wq * 16)) {
        #pragma unroll
        for (int jt = 0; jt < 4; ++jt)
          #pragma unroll
          for (int r = 0; r < 4; ++r)
            if (j0 + jt * 16 + l15 > qr0 + r) S[jt][r] = NEG_INF;
      }

      // online softmax: rows = quad*4+r, cols across 16 lanes of the quad group
      float alpha[4], rsum[4];
      #pragma unroll
      for (int r = 0; r < 4; ++r) {
        float mx = fmaxf(fmaxf(S[0][r], S[1][r]), fmaxf(S[2][r], S[3][r]));
        #pragma unroll
        for (int w = 1; w <= 8; w <<= 1) mx = fmaxf(mx, __shfl_xor(mx, w));
        float mn = fmaxf(mrow[r], mx);
        alpha[r] = __expf(mrow[r] - mn);
        mrow[r] = mn;
        rsum[r] = 0.f;
      }
      #pragma unroll
      for (int jt = 0; jt < 4; ++jt)
        #pragma unroll
        for (int r = 0; r < 4; ++r) {
          float p = __expf(S[jt][r] - mrow[r]);   // masked -> exp(-inf) = 0
          rsum[r] += p;
          Pw[(quad * 4 + r) * PSTR + jt * 16 + l15] = bf16_bits(p);
        }
      #pragma unroll
      for (int r = 0; r < 4; ++r) {
        float s = rsum[r];
        #pragma unroll
        for (int w = 1; w <= 8; w <<= 1) s += __shfl_xor(s, w);
        lrow[r] = lrow[r] * alpha[r] + s;
      }
      // rescale O
      #pragma unroll
      for (int dt = 0; dt < 8; ++dt)
        #pragma unroll
        for (int r = 0; r < 4; ++r) Ot[dt][r] *= alpha[r];

      // O += P V : A = P[m=q][k=kv], B = V[n=d][k=kv]
      #pragma unroll
      for (int kc = 0; kc < 2; ++kc) {
        bf16x8 pf = *(const bf16x8*)&Pw[l15 * PSTR + kc * 32 + quad * 8];
        #pragma unroll
        for (int dt = 0; dt < 8; ++dt) {
          bf16x8 vf = *(const bf16x8*)&Vs[(dt * 16 + l15) * 64 + ((kc * 32 + quad * 8) ^ swz)];
          Ot[dt] = __builtin_amdgcn_mfma_f32_16x16x32_bf16(pf, vf, Ot[dt], 0, 0, 0);
        }
      }
    }

    // write next tile to LDS after all waves finished reading this one
    if (tile + 1 < ntiles) {
      __syncthreads();
      #pragma unroll
      for (int it = 0; it < 2; ++it) {
        int idx = it * 512 + tid;
        int r = idx >> 4, c8 = idx & 15;
        *(ushort8v*)&Ks[r * 128 + ((c8 ^ (r & 7)) * 8)] = kreg[it];
        int d = idx >> 3, c8v = idx & 7;
        *(ushort8v*)&Vs[d * 64 + ((c8v ^ (d & 7)) * 8)] = vreg[it];
      }
      __syncthreads();
    }
  }

  // epilogue: normalize and store
  float invl[4];
  #pragma unroll
  for (int r = 0; r < 4; ++r) invl[r] = 1.f / lrow[r];
  #pragma unroll
  for (int dt = 0; dt < 8; ++dt)
    #pragma unroll
    for (int r = 0; r < 4; ++r)
      o[(size_t)(b * TSEQ + m0 + wq * 16 + quad * 4 + r) * CDIM + h * DH + dt * 16 + l15] =
          __float2bfloat16(Ot[dt][r] * invl[r]);
}

// ---------------- launch ----------------
extern "C" void kernel_launch(void* const* d_in, const int* in_sizes, int n_in,
                              void* d_out, int out_size, void* d_ws, size_t ws_size,
                              hipStream_t stream) {
  const float* x    = (const float*)d_in[0];
  const float* wq   = (const float*)d_in[1];
  const float* wk   = (const float*)d_in[2];
  const float* wv   = (const float*)d_in[3];
  const float* wo   = (const float*)d_in[4];
  const float* cosb = (const float*)d_in[5];
  const float* sinb = (const float*)d_in[6];
  const int* causal = (const int*)d_in[7];

  char* wsb = (char*)d_ws;
  __hip_bfloat16* xb   = (__hip_bfloat16*)(wsb);
  __hip_bfloat16* woT  = (__hip_bfloat16*)(wsb);
  __hip_bfloat16* wqT  = (__hip_bfloat16*)(wsb + (((size_t)32) << 20));
  __hip_bfloat16* obuf = (__hip_bfloat16*)(wsb + (((size_t)32) << 20));
  __hip_bfloat16* wkvT = (__hip_bfloat16*)(wsb + (((size_t)64) << 20));
  u16*            vtb  = (u16*)           (wsb + (((size_t)64) << 20));
  __hip_bfloat16* kvb  = (__hip_bfloat16*)(wsb + (((size_t)80) << 20));
  __hip_bfloat16* qb   = (__hip_bfloat16*)d_out;

  dim3 blk(256);
  dim3 blk5(512);
  cvt_bf16x4<<<dim3((BT * CDIM / 4 + 255) / 256), blk, 0, stream>>>(x, xb, BT * CDIM / 4);
  transpose_cvt<<<dim3(CDIM / 64, CDIM / 64), blk, 0, stream>>>(wq, wqT, CDIM, CDIM);
  transpose_cvt<<<dim3(1024 / 64, CDIM / 64), blk, 0, stream>>>(wk, wkvT, CDIM, 1024);
  transpose_cvt<<<dim3(1024 / 64, CDIM / 64), blk, 0, stream>>>(wv, wkvT + (size_t)1024 * CDIM, CDIM, 1024);
  gemm256<<<dim3(CDIM / 256, BT / 256), blk5, 0, stream>>>(xb, wqT, qb, CDIM, CDIM, 1);
  gemm_mfma<<<dim3(2048 / 128, BT / 128), blk, 0, stream>>>(xb, wkvT, kvb, 2048, CDIM, 1);
  transpose_v<<<dim3(32, NKV, BSZ), blk, 0, stream>>>(kvb, vtb);
  rope_bf16<<<dim3(BT * (CDIM / 8) / 256), blk, 0, stream>>>(qb, CDIM, CDIM / 8, cosb, sinb);
  rope_bf16<<<dim3(BT * (1024 / 8) / 256), blk, 0, stream>>>(kvb, 2048, 1024 / 8, cosb, sinb);
  transpose_cvt<<<dim3(CDIM / 64, CDIM / 64), blk, 0, stream>>>(wo, woT, CDIM, CDIM);
  flash_mfma<<<dim3(TSEQ / 128, NH, BSZ), blk5, 0, stream>>>(qb, kvb, vtb, obuf, causal);
  gemm256<<<dim3(CDIM / 256, BT / 256), blk5, 0, stream>>>(obuf, woT, d_out, CDIM, CDIM, 0);
}

// Round 16
// 899.463 us; speedup vs baseline: 1.3261x; 1.0405x over previous
//
#include <hip/hip_runtime.h>
#include <hip/hip_bf16.h>

// Problem constants
#define BSZ   2
#define TSEQ  2048
#define CDIM  4096
#define NH    32
#define NKV   8
#define GQ    4
#define DH    128
#define BT    (BSZ * TSEQ)   // 4096

typedef short   bf16x8  __attribute__((ext_vector_type(8)));
typedef float   f32x4   __attribute__((ext_vector_type(4)));
typedef unsigned short ushort8v __attribute__((ext_vector_type(8)));
typedef unsigned short u16;

#define LDS_AS(p) ((__attribute__((address_space(3))) void*)(p))
#define GLB_AS(p) ((const __attribute__((address_space(1))) void*)(p))

static __device__ inline unsigned short bf16_bits(float f) {
  __hip_bfloat16 h = __float2bfloat16(f);
  return *(unsigned short*)&h;
}
static __device__ inline float bits_f32(unsigned short u) {
  unsigned v = ((unsigned)u) << 16;
  return __builtin_bit_cast(float, v);
}

// ---------------- fp32 -> bf16 elementwise ----------------
__global__ __launch_bounds__(256) void cvt_bf16x4(
    const float* __restrict__ src, __hip_bfloat16* __restrict__ dst, int n4) {
  int i = blockIdx.x * 256 + threadIdx.x;
  if (i >= n4) return;
  float4 v = ((const float4*)src)[i];
  ushort4 o;
  o.x = bf16_bits(v.x); o.y = bf16_bits(v.y);
  o.z = bf16_bits(v.z); o.w = bf16_bits(v.w);
  ((ushort4*)dst)[i] = o;
}

// ---------------- transpose + convert: src K x N fp32 -> dst N x K bf16 ----------------
__global__ __launch_bounds__(256) void transpose_cvt(
    const float* __restrict__ src, __hip_bfloat16* __restrict__ dst, int K, int N) {
  __shared__ float T[64][65];
  const int bn = blockIdx.x * 64;
  const int bk = blockIdx.y * 64;
  const int tid = threadIdx.x;
  for (int i = tid; i < 64 * 16; i += 256) {
    int r = i >> 4, c4 = i & 15;
    float4 v = *(const float4*)&src[(size_t)(bk + r) * N + bn + c4 * 4];
    T[r][c4*4+0] = v.x; T[r][c4*4+1] = v.y; T[r][c4*4+2] = v.z; T[r][c4*4+3] = v.w;
  }
  __syncthreads();
  for (int i = tid; i < 64 * 16; i += 256) {
    int n = i >> 4, k4 = i & 15;
    ushort4 o;
    o.x = bf16_bits(T[k4*4+0][n]); o.y = bf16_bits(T[k4*4+1][n]);
    o.z = bf16_bits(T[k4*4+2][n]); o.w = bf16_bits(T[k4*4+3][n]);
    *(ushort4*)&dst[(size_t)(bn + n) * K + bk + k4 * 4] = o;
  }
}

// ---------------- bf16 MFMA GEMM (m97 structure) — kept for KV GEMM (N=2048) ----------------
__global__ __launch_bounds__(256) void gemm_mfma(
    const __hip_bfloat16* __restrict__ A, const __hip_bfloat16* __restrict__ Bt,
    void* __restrict__ C, int N, int K, int outBf16) {
  __shared__ __hip_bfloat16 As[128 * 32];
  __shared__ __hip_bfloat16 Bs[128 * 32];
  const int tid  = threadIdx.x;
  const int lane = tid & 63;
  const int wv   = tid >> 6;
  const int row0 = blockIdx.y * 128;
  const int col0 = blockIdx.x * 128;
  const int wm   = (wv & 1) * 64;
  const int wn   = (wv >> 1) * 64;
  const int lrow = lane & 15;
  const int kgrp = lane >> 4;

  f32x4 zero = {0.f, 0.f, 0.f, 0.f};
  f32x4 acc[4][4];
  #pragma unroll
  for (int mi = 0; mi < 4; ++mi)
    #pragma unroll
    for (int ni = 0; ni < 4; ++ni) acc[mi][ni] = zero;

  for (int k0 = 0; k0 < K; k0 += 32) {
    #pragma unroll
    for (int r = 0; r < 2; ++r) {
      int idx16 = r * 256 + tid;
      int arow  = idx16 >> 2;
      int akk   = (idx16 & 3) << 3;
      const __hip_bfloat16* ga = &A [(size_t)(row0 + arow) * K + k0 + akk];
      const __hip_bfloat16* gb = &Bt[(size_t)(col0 + arow) * K + k0 + akk];
      char* la = (char*)As + (r * 4096 + wv * 1024 + lane * 16);
      char* lb = (char*)Bs + (r * 4096 + wv * 1024 + lane * 16);
      __builtin_amdgcn_global_load_lds(GLB_AS(ga), LDS_AS(la), 16, 0, 0);
      __builtin_amdgcn_global_load_lds(GLB_AS(gb), LDS_AS(lb), 16, 0, 0);
    }
    __syncthreads();
    bf16x8 af[4], bfr[4];
    #pragma unroll
    for (int i = 0; i < 4; ++i) {
      af[i]  = *(const bf16x8*)&As[(wm + i * 16 + lrow) * 32 + kgrp * 8];
      bfr[i] = *(const bf16x8*)&Bs[(wn + i * 16 + lrow) * 32 + kgrp * 8];
    }
    #pragma unroll
    for (int mi = 0; mi < 4; ++mi)
      #pragma unroll
      for (int ni = 0; ni < 4; ++ni)
        acc[mi][ni] = __builtin_amdgcn_mfma_f32_16x16x32_bf16(af[mi], bfr[ni], acc[mi][ni], 0, 0, 0);
    __syncthreads();
  }

  if (outBf16) {
    __hip_bfloat16* Cb = (__hip_bfloat16*)C;
    #pragma unroll
    for (int mi = 0; mi < 4; ++mi)
      #pragma unroll
      for (int ni = 0; ni < 4; ++ni) {
        int col = col0 + wn + ni * 16 + lrow;
        int rowb = row0 + wm + mi * 16 + kgrp * 4;
        #pragma unroll
        for (int r = 0; r < 4; ++r)
          Cb[(size_t)(rowb + r) * N + col] = __float2bfloat16(acc[mi][ni][r]);
      }
  } else {
    float* Cf = (float*)C;
    #pragma unroll
    for (int mi = 0; mi < 4; ++mi)
      #pragma unroll
      for (int ni = 0; ni < 4; ++ni) {
        int col = col0 + wn + ni * 16 + lrow;
        int rowb = row0 + wm + mi * 16 + kgrp * 4;
        #pragma unroll
        for (int r = 0; r < 4; ++r)
          Cf[(size_t)(rowb + r) * N + col] = acc[mi][ni][r];
      }
  }
}

// ---------------- 256x256 8-phase bf16 MFMA GEMM (m201 template, plain HIP) ----------------
__global__ __launch_bounds__(512, 2) void gemm256(
    const __hip_bfloat16* __restrict__ A, const __hip_bfloat16* __restrict__ Bt,
    void* __restrict__ C, int N, int K, int outBf16) {
  __shared__ __hip_bfloat16 AsBuf[2][16384];   // [buf][256 rows x 64 k]
  __shared__ __hip_bfloat16 BsBuf[2][16384];

  const int tid  = threadIdx.x;
  const int lane = tid & 63;
  const int wid  = tid >> 6;
  const int wm   = wid >> 2;        // 0..1
  const int wn   = wid & 3;         // 0..3
  const int quad = lane >> 4;
  const int l15  = lane & 15;

  // XCD-aware block swizzle (bijective when nwg % 8 == 0)
  const int nbx = N >> 8;
  int bid = blockIdx.y * nbx + blockIdx.x;
  const int nwg = nbx * (int)gridDim.y;
  if ((nwg & 7) == 0) bid = (bid & 7) * (nwg >> 3) + (bid >> 3);
  const int row0 = (bid / nbx) << 8;
  const int col0 = (bid % nbx) << 8;

  const int NT = K >> 6;

  // fragment-read element offsets (swizzled): row&7 == l15&7 for all frag rows
  const int xr  = (l15 & 7) << 4;                  // byte XOR, bits 4-6
  const int ke0 = (((quad * 16)      ^ xr) >> 1);  // kc=0, elements
  const int ke1 = (((64 + quad * 16) ^ xr) >> 1);  // kc=1
  const int arE = (wm * 128 + l15) * 64;           // A row base, elements
  const int brE = (wn * 64  + l15) * 64;           // B row base, elements

  // Stage one 128-row half-tile (16 KiB): linear LDS dest, inverse-swizzled global src.
#define STG(srcp, r0g, ldsb, h, k0e) do {                                          \
    _Pragma("unroll")                                                              \
    for (int j = 0; j < 2; ++j) {                                                  \
      int p    = (j * 512 + tid) << 4;               /* byte in half-tile */       \
      int prow = p >> 7;                                                           \
      int koff = (p & 127) ^ ((prow & 7) << 4);                                    \
      const __hip_bfloat16* gsrc =                                                 \
          (srcp) + (size_t)((r0g) + (h) * 128 + prow) * K + (k0e) + (koff >> 1);   \
      char* ldst = (char*)(ldsb) + (h) * 16384 + p;                                \
      __builtin_amdgcn_global_load_lds(GLB_AS(gsrc), LDS_AS(ldst), 16, 0, 0);      \
    }                                                                              \
  } while (0)

  f32x4 acc[8][4];
  #pragma unroll
  for (int i = 0; i < 8; ++i)
    #pragma unroll
    for (int j = 0; j < 4; ++j) acc[i][j] = (f32x4){0.f, 0.f, 0.f, 0.f};

  // prologue: tile0 complete + tile1 B-halves (A-halves of tile1 come in phases 1-2 of t=0)
  STG(A,  row0, &AsBuf[0][0], 0, 0);
  STG(A,  row0, &AsBuf[0][0], 1, 0);
  STG(Bt, col0, &BsBuf[0][0], 0, 0);
  STG(Bt, col0, &BsBuf[0][0], 1, 0);
  if (NT > 1) {
    STG(Bt, col0, &BsBuf[1][0], 0, 64);
    STG(Bt, col0, &BsBuf[1][0], 1, 64);
    asm volatile("s_waitcnt vmcnt(4)" ::: "memory");   // tile0 landed, tile1 B in flight
  } else {
    asm volatile("s_waitcnt vmcnt(0)" ::: "memory");
  }
  __builtin_amdgcn_s_barrier();

  for (int t = 0; t < NT; ++t) {
    const int d  = t & 1, od = d ^ 1;
    char* Aod = (char*)&AsBuf[od][0];
    char* Bd  = (char*)&BsBuf[d][0];
    const int k1 = (t + 1) << 6, k2 = (t + 2) << 6;
    bf16x8 aH[4][2], b0[2][2], b1[2][2];

    // ---- phase 1 : Q0 = (M0, N0) ; stage A-half0(t+1) into other buf ----
    #pragma unroll
    for (int m = 0; m < 4; ++m) {
      aH[m][0] = *(const bf16x8*)&AsBuf[d][arE + m * 1024 + ke0];
      aH[m][1] = *(const bf16x8*)&AsBuf[d][arE + m * 1024 + ke1];
    }
    #pragma unroll
    for (int n = 0; n < 2; ++n) {
      b0[n][0] = *(const bf16x8*)&BsBuf[d][brE + n * 1024 + ke0];
      b0[n][1] = *(const bf16x8*)&BsBuf[d][brE + n * 1024 + ke1];
    }
    if (t + 1 < NT) STG(A, row0, Aod, 0, k1);
    __builtin_amdgcn_s_barrier();
    asm volatile("s_waitcnt lgkmcnt(0)" ::: "memory");
    __builtin_amdgcn_s_setprio(1);
    #pragma unroll
    for (int m = 0; m < 4; ++m)
      #pragma unroll
      for (int n = 0; n < 2; ++n) {
        acc[m][n] = __builtin_amdgcn_mfma_f32_16x16x32_bf16(aH[m][0], b0[n][0], acc[m][n], 0, 0, 0);
        acc[m][n] = __builtin_amdgcn_mfma_f32_16x16x32_bf16(aH[m][1], b0[n][1], acc[m][n], 0, 0, 0);
      }
    __builtin_amdgcn_s_setprio(0);
    __builtin_amdgcn_s_barrier();

    // ---- phase 2 : Q1 = (M0, N1) ; stage A-half1(t+1) ----
    #pragma unroll
    for (int n = 0; n < 2; ++n) {
      b1[n][0] = *(const bf16x8*)&BsBuf[d][brE + (n + 2) * 1024 + ke0];
      b1[n][1] = *(const bf16x8*)&BsBuf[d][brE + (n + 2) * 1024 + ke1];
    }
    if (t + 1 < NT) STG(A, row0, Aod, 1, k1);
    __builtin_amdgcn_s_barrier();
    asm volatile("s_waitcnt lgkmcnt(0)" ::: "memory");
    __builtin_amdgcn_s_setprio(1);
    #pragma unroll
    for (int m = 0; m < 4; ++m)
      #pragma unroll
      for (int n = 0; n < 2; ++n) {
        acc[m][n + 2] = __builtin_amdgcn_mfma_f32_16x16x32_bf16(aH[m][0], b1[n][0], acc[m][n + 2], 0, 0, 0);
        acc[m][n + 2] = __builtin_amdgcn_mfma_f32_16x16x32_bf16(aH[m][1], b1[n][1], acc[m][n + 2], 0, 0, 0);
      }
    __builtin_amdgcn_s_setprio(0);
    __builtin_amdgcn_s_barrier();

    // ---- phase 3 : Q2 = (M1, N1) ; stage B-half0(t+2) into own buf (B reads done @ph2) ----
    #pragma unroll
    for (int m = 0; m < 4; ++m) {
      aH[m][0] = *(const bf16x8*)&AsBuf[d][arE + 4096 + m * 1024 + ke0];
      aH[m][1] = *(const bf16x8*)&AsBuf[d][arE + 4096 + m * 1024 + ke1];
    }
    if (t + 2 < NT) STG(Bt, col0, Bd, 0, k2);
    __builtin_amdgcn_s_barrier();
    asm volatile("s_waitcnt lgkmcnt(0)" ::: "memory");
    __builtin_amdgcn_s_setprio(1);
    #pragma unroll
    for (int m = 0; m < 4; ++m)
      #pragma unroll
      for (int n = 0; n < 2; ++n) {
        acc[m + 4][n + 2] = __builtin_amdgcn_mfma_f32_16x16x32_bf16(aH[m][0], b1[n][0], acc[m + 4][n + 2], 0, 0, 0);
        acc[m + 4][n + 2] = __builtin_amdgcn_mfma_f32_16x16x32_bf16(aH[m][1], b1[n][1], acc[m + 4][n + 2], 0, 0, 0);
      }
    __builtin_amdgcn_s_setprio(0);
    __builtin_amdgcn_s_barrier();

    // ---- phase 4 : Q3 = (M1, N0) (all frags in regs) ; stage B-half1(t+2) ----
    if (t + 2 < NT) STG(Bt, col0, Bd, 1, k2);
    __builtin_amdgcn_s_barrier();
    __builtin_amdgcn_s_setprio(1);
    #pragma unroll
    for (int m = 0; m < 4; ++m)
      #pragma unroll
      for (int n = 0; n < 2; ++n) {
        acc[m + 4][n] = __builtin_amdgcn_mfma_f32_16x16x32_bf16(aH[m][0], b0[n][0], acc[m + 4][n], 0, 0, 0);
        acc[m + 4][n] = __builtin_amdgcn_mfma_f32_16x16x32_bf16(aH[m][1], b0[n][1], acc[m + 4][n], 0, 0, 0);
      }
    __builtin_amdgcn_s_setprio(0);
    // boundary: tile t+1's A-halves must be landed; keep B(t+2) (4 loads) in flight
    if (t < NT - 2)       asm volatile("s_waitcnt vmcnt(4)" ::: "memory");
    else if (t == NT - 2) asm volatile("s_waitcnt vmcnt(0)" ::: "memory");
    __builtin_amdgcn_s_barrier();
  }
#undef STG

  if (outBf16) {
    __hip_bfloat16* Cb = (__hip_bfloat16*)C;
    #pragma unroll
    for (int mi = 0; mi < 8; ++mi)
      #pragma unroll
      for (int ni = 0; ni < 4; ++ni) {
        int col  = col0 + wn * 64 + ni * 16 + l15;
        int rowb = row0 + wm * 128 + mi * 16 + quad * 4;
        #pragma unroll
        for (int r = 0; r < 4; ++r)
          Cb[(size_t)(rowb + r) * N + col] = __float2bfloat16(acc[mi][ni][r]);
      }
  } else {
    float* Cf = (float*)C;
    #pragma unroll
    for (int mi = 0; mi < 8; ++mi)
      #pragma unroll
      for (int ni = 0; ni < 4; ++ni) {
        int col  = col0 + wn * 64 + ni * 16 + l15;
        int rowb = row0 + wm * 128 + mi * 16 + quad * 4;
        #pragma unroll
        for (int r = 0; r < 4; ++r)
          Cf[(size_t)(rowb + r) * N + col] = acc[mi][ni][r];
      }
  }
}

// ---------------- RoPE on a bf16 buffer ----------------
__global__ __launch_bounds__(256) void rope_bf16(
    __hip_bfloat16* __restrict__ buf, int stride, int perRow,
    const float* __restrict__ cosb, const float* __restrict__ sinb) {
  int idx = blockIdx.x * 256 + threadIdx.x;
  int row = idx / perRow;
  if (row >= BT) return;
  int c8 = (idx - row * perRow) * 8;
  int t  = row & (TSEQ - 1);
  int cp = c8 & (DH - 1);
  __hip_bfloat16* p = buf + (size_t)row * stride + c8;
  ushort8v raw = *(const ushort8v*)p;
  const float* cr = &cosb[(size_t)t * DH + cp];
  const float* sr = &sinb[(size_t)t * DH + cp];
  ushort8v outp;
  #pragma unroll
  for (int j = 0; j < 8; j += 2) {
    float x1 = bits_f32(raw[j]), x2 = bits_f32(raw[j + 1]);
    float c = cr[j], s = sr[j];
    outp[j]     = bf16_bits(x1 * c - x2 * s);
    outp[j + 1] = bf16_bits(x1 * s + x2 * c);
  }
  *(ushort8v*)p = outp;
}

// ---------------- V transpose into dense per-(b,kvh,tile) 128x64 blobs ----------------
__global__ __launch_bounds__(256) void transpose_v(
    const __hip_bfloat16* __restrict__ kvsrc, u16* __restrict__ vt) {
  __shared__ u16 T[64][72];
  const int tid  = threadIdx.x;
  const int tile = blockIdx.x, kvh = blockIdx.y, b = blockIdx.z;
  u16* dst = vt + ((size_t)((b * NKV + kvh) * 32 + tile)) * (128 * 64);
  for (int half = 0; half < 2; ++half) {
    #pragma unroll
    for (int it = 0; it < 2; ++it) {
      int idx = it * 256 + tid;          // 512 chunks = 64 t x 8 d-chunks
      int r = idx >> 3, c8 = idx & 7;
      ushort8v vdat = *(const ushort8v*)&kvsrc[
          (size_t)(b * TSEQ + tile * 64 + r) * 2048 + 1024 + kvh * DH + half * 64 + c8 * 8];
      *(ushort8v*)&T[r][c8 * 8] = vdat;
    }
    __syncthreads();
    #pragma unroll
    for (int it = 0; it < 2; ++it) {
      int idx = it * 256 + tid;
      int d = idx >> 3, c8 = idx & 7;    // d row of output, c8: t-chunk
      ushort8v o8;
      #pragma unroll
      for (int j = 0; j < 8; ++j) o8[j] = T[c8 * 8 + j][d];
      *(ushort8v*)&dst[(size_t)(half * 64 + d) * 64 + c8 * 8] = o8;
    }
    __syncthreads();
  }
}

// ---------------- MFMA flash attention ----------------
// 8-wave QBLK=128 (measured 334us). This round, softmax-chain cuts only:
//  (1) row-sum via MFMA-with-ones accumulator Osum (kills the 16-shuffle sum
//      tree + lrow arithmetic; denominator sums the same bf16 P fed to PV)
//  (2) defer-max (T13, THR=8): skip alpha/rescale/mrow-update unless
//      __any(pmax > mrow+8) wave-wide. First tile (mrow=-inf) rescales.
#define PSTR 68    // Ps row stride

__global__ __launch_bounds__(512, 4) void flash_mfma(
    const __hip_bfloat16* __restrict__ q,    // (BT, 4096)
    const __hip_bfloat16* __restrict__ kv,   // kvb (BT, 2048); k at col kvh*128
    const u16* __restrict__ vt,              // V^T blobs
    __hip_bfloat16* __restrict__ o,          // (BT, 4096)
    const int* __restrict__ causal_p) {
  __shared__ u16 Ks[64 * 128];      // [kv][d], swizzled
  __shared__ u16 Vs[128 * 64];      // [d][kv], swizzled
  __shared__ u16 Ps[8][16 * PSTR];  // per-wave [q][kv]

  const int tid  = threadIdx.x;
  const int lane = tid & 63;
  const int wq   = tid >> 6;        // 0..7
  const int quad = lane >> 4;
  const int l15  = lane & 15;
  const int mtile = (int)gridDim.x - 1 - (int)blockIdx.x;   // LPT order
  const int h = blockIdx.y, b = blockIdx.z;
  const int kvh = h >> 2;
  const int m0  = mtile * 128;
  const bool causal = (*causal_p != 0);
  const float NEG_INF = -__builtin_inff();
  const float scale = 0.08838834764831845f;
  const int swz = (l15 & 7) << 3;   // element XOR for this lane's LDS reads
  const int qr0 = m0 + wq * 16 + quad * 4;   // this thread's first q row
  const int qrMax = m0 + wq * 16 + 15;       // wave's last q row

  bf16x8 qf[4];
  {
    const __hip_bfloat16* qrow =
        &q[(size_t)(b * TSEQ + m0 + wq * 16 + l15) * CDIM + h * DH + quad * 8];
    #pragma unroll
    for (int kc = 0; kc < 4; ++kc) qf[kc] = *(const bf16x8*)(qrow + kc * 32);
  }
  bf16x8 onesf;
  #pragma unroll
  for (int j = 0; j < 8; ++j) onesf[j] = (short)0x3F80;   // bf16 1.0

  f32x4 Ot[8];
  #pragma unroll
  for (int dt = 0; dt < 8; ++dt) Ot[dt] = (f32x4){0.f, 0.f, 0.f, 0.f};
  f32x4 Osum = {0.f, 0.f, 0.f, 0.f};     // row-sum accumulator (MFMA-ones)
  float mrow[4] = {NEG_INF, NEG_INF, NEG_INF, NEG_INF};

  const int ntiles = causal ? (2 * mtile + 2) : (TSEQ / 64);
  u16* Pw = &Ps[wq][0];
  const u16* vtbase = vt + ((size_t)(b * NKV + kvh) * 32) * (128 * 64);

  ushort8v kreg[2], vreg[2];
  // prologue: stage K/V tile 0 (1024 chunks each, 512 threads, 2 iters)
  #pragma unroll
  for (int it = 0; it < 2; ++it) {
    int idx = it * 512 + tid;
    int r = idx >> 4, c8 = idx & 15;
    kreg[it] = *(const ushort8v*)&kv[(size_t)(b * TSEQ + r) * 2048 + kvh * DH + c8 * 8];
    int d = idx >> 3, c8v = idx & 7;
    vreg[it] = *(const ushort8v*)&vtbase[(size_t)d * 64 + c8v * 8];
  }
  #pragma unroll
  for (int it = 0; it < 2; ++it) {
    int idx = it * 512 + tid;
    int r = idx >> 4, c8 = idx & 15;
    *(ushort8v*)&Ks[r * 128 + ((c8 ^ (r & 7)) * 8)] = kreg[it];
    int d = idx >> 3, c8v = idx & 7;
    *(ushort8v*)&Vs[d * 64 + ((c8v ^ (d & 7)) * 8)] = vreg[it];
  }
  __syncthreads();

  for (int tile = 0; tile < ntiles; ++tile) {
    const int j0 = tile * 64;
    // prefetch next K/V tile into registers (latency hides under compute)
    if (tile + 1 < ntiles) {
      const u16* vblob = vtbase + (size_t)(tile + 1) * (128 * 64);
      #pragma unroll
      for (int it = 0; it < 2; ++it) {
        int idx = it * 512 + tid;
        int r = idx >> 4, c8 = idx & 15;
        kreg[it] = *(const ushort8v*)&kv[(size_t)(b * TSEQ + j0 + 64 + r) * 2048 + kvh * DH + c8 * 8];
        int d = idx >> 3, c8v = idx & 7;
        vreg[it] = *(const ushort8v*)&vblob[(size_t)d * 64 + c8v * 8];
      }
    }

    // waves whose q-rows all precede this kv tile skip compute (wave-uniform)
    const bool active = !causal || (j0 <= qrMax);
    if (active) {
      // S = Q K^T : 4 kv 16-tiles x 4 d-chunks
      f32x4 S[4];
      #pragma unroll
      for (int jt = 0; jt < 4; ++jt) {
        f32x4 acc = {0.f, 0.f, 0.f, 0.f};
        #pragma unroll
        for (int kc = 0; kc < 4; ++kc) {
          bf16x8 kf = *(const bf16x8*)&Ks[(jt * 16 + l15) * 128 + ((kc * 32 + quad * 8) ^ swz)];
          acc = __builtin_amdgcn_mfma_f32_16x16x32_bf16(qf[kc], kf, acc, 0, 0, 0);
        }
        S[jt] = acc;
      }
      #pragma unroll
      for (int jt = 0; jt < 4; ++jt)
        #pragma unroll
        for (int r = 0; r < 4; ++r) S[jt][r] *= scale;
      if (causal && (j0 + 63 > m0 + wq * 16)) {
        #pragma unroll
        for (int jt = 0; jt < 4; ++jt)
          #pragma unroll
          for (int r = 0; r < 4; ++r)
            if (j0 + jt * 16 + l15 > qr0 + r) S[jt][r] = NEG_INF;
      }

      // per-row tile max (local + quad-group shuffle tree)
      float pmax[4];
      #pragma unroll
      for (int r = 0; r < 4; ++r) {
        float mx = fmaxf(fmaxf(S[0][r], S[1][r]), fmaxf(S[2][r], S[3][r]));
        #pragma unroll
        for (int w = 1; w <= 8; w <<= 1) mx = fmaxf(mx, __shfl_xor(mx, w));
        pmax[r] = mx;
      }
      // defer-max: only rescale when some row grew past THR=8
      bool need = false;
      #pragma unroll
      for (int r = 0; r < 4; ++r) need = need || (pmax[r] > mrow[r] + 8.f);
      if (__any(need ? 1 : 0)) {
        float alpha[4];
        #pragma unroll
        for (int r = 0; r < 4; ++r) {
          float mn = fmaxf(mrow[r], pmax[r]);
          alpha[r] = __expf(mrow[r] - mn);
          mrow[r] = mn;
        }
        #pragma unroll
        for (int dt = 0; dt < 8; ++dt)
          #pragma unroll
          for (int r = 0; r < 4; ++r) Ot[dt][r] *= alpha[r];
        #pragma unroll
        for (int r = 0; r < 4; ++r) Osum[r] *= alpha[r];
      }
      // P = exp(S - mrow), store bf16 to per-wave Ps
      #pragma unroll
      for (int jt = 0; jt < 4; ++jt)
        #pragma unroll
        for (int r = 0; r < 4; ++r) {
          float p = __expf(S[jt][r] - mrow[r]);   // masked -> exp(-inf) = 0
          Pw[(quad * 4 + r) * PSTR + jt * 16 + l15] = bf16_bits(p);
        }

      // O += P V ; Osum += P * 1 (row-sum via MFMA, replaces shuffle sum-tree)
      #pragma unroll
      for (int kc = 0; kc < 2; ++kc) {
        bf16x8 pf = *(const bf16x8*)&Pw[l15 * PSTR + kc * 32 + quad * 8];
        Osum = __builtin_amdgcn_mfma_f32_16x16x32_bf16(pf, onesf, Osum, 0, 0, 0);
        #pragma unroll
        for (int dt = 0; dt < 8; ++dt) {
          bf16x8 vf = *(const bf16x8*)&Vs[(dt * 16 + l15) * 64 + ((kc * 32 + quad * 8) ^ swz)];
          Ot[dt] = __builtin_amdgcn_mfma_f32_16x16x32_bf16(pf, vf, Ot[dt], 0, 0, 0);
        }
      }
    }

    // write next tile to LDS after all waves finished reading this one
    if (tile + 1 < ntiles) {
      __syncthreads();
      #pragma unroll
      for (int it = 0; it < 2; ++it) {
        int idx = it * 512 + tid;
        int r = idx >> 4, c8 = idx & 15;
        *(ushort8v*)&Ks[r * 128 + ((c8 ^ (r & 7)) * 8)] = kreg[it];
        int d = idx >> 3, c8v = idx & 7;
        *(ushort8v*)&Vs[d * 64 + ((c8v ^ (d & 7)) * 8)] = vreg[it];
      }
      __syncthreads();
    }
  }

  // epilogue: normalize and store (Osum[r] = row denominator, broadcast in quad)
  float invl[4];
  #pragma unroll
  for (int r = 0; r < 4; ++r) invl[r] = 1.f / Osum[r];
  #pragma unroll
  for (int dt = 0; dt < 8; ++dt)
    #pragma unroll
    for (int r = 0; r < 4; ++r)
      o[(size_t)(b * TSEQ + m0 + wq * 16 + quad * 4 + r) * CDIM + h * DH + dt * 16 + l15] =
          __float2bfloat16(Ot[dt][r] * invl[r]);
}

// ---------------- launch ----------------
extern "C" void kernel_launch(void* const* d_in, const int* in_sizes, int n_in,
                              void* d_out, int out_size, void* d_ws, size_t ws_size,
                              hipStream_t stream) {
  const float* x    = (const float*)d_in[0];
  const float* wq   = (const float*)d_in[1];
  const float* wk   = (const float*)d_in[2];
  const float* wv   = (const float*)d_in[3];
  const float* wo   = (const float*)d_in[4];
  const float* cosb = (const float*)d_in[5];
  const float* sinb = (const float*)d_in[6];
  const int* causal = (const int*)d_in[7];

  char* wsb = (char*)d_ws;
  __hip_bfloat16* xb   = (__hip_bfloat16*)(wsb);
  __hip_bfloat16* woT  = (__hip_bfloat16*)(wsb);
  __hip_bfloat16* wqT  = (__hip_bfloat16*)(wsb + (((size_t)32) << 20));
  __hip_bfloat16* obuf = (__hip_bfloat16*)(wsb + (((size_t)32) << 20));
  __hip_bfloat16* wkvT = (__hip_bfloat16*)(wsb + (((size_t)64) << 20));
  u16*            vtb  = (u16*)           (wsb + (((size_t)64) << 20));
  __hip_bfloat16* kvb  = (__hip_bfloat16*)(wsb + (((size_t)80) << 20));
  __hip_bfloat16* qb   = (__hip_bfloat16*)d_out;

  dim3 blk(256);
  dim3 blk5(512);
  cvt_bf16x4<<<dim3((BT * CDIM / 4 + 255) / 256), blk, 0, stream>>>(x, xb, BT * CDIM / 4);
  transpose_cvt<<<dim3(CDIM / 64, CDIM / 64), blk, 0, stream>>>(wq, wqT, CDIM, CDIM);
  transpose_cvt<<<dim3(1024 / 64, CDIM / 64), blk, 0, stream>>>(wk, wkvT, CDIM, 1024);
  transpose_cvt<<<dim3(1024 / 64, CDIM / 64), blk, 0, stream>>>(wv, wkvT + (size_t)1024 * CDIM, CDIM, 1024);
  gemm256<<<dim3(CDIM / 256, BT / 256), blk5, 0, stream>>>(xb, wqT, qb, CDIM, CDIM, 1);
  gemm_mfma<<<dim3(2048 / 128, BT / 128), blk, 0, stream>>>(xb, wkvT, kvb, 2048, CDIM, 1);
  transpose_v<<<dim3(32, NKV, BSZ), blk, 0, stream>>>(kvb, vtb);
  rope_bf16<<<dim3(BT * (CDIM / 8) / 256), blk, 0, stream>>>(qb, CDIM, CDIM / 8, cosb, sinb);
  rope_bf16<<<dim3(BT * (1024 / 8) / 256), blk, 0, stream>>>(kvb, 2048, 1024 / 8, cosb, sinb);
  transpose_cvt<<<dim3(CDIM / 64, CDIM / 64), blk, 0, stream>>>(wo, woT, CDIM, CDIM);
  flash_mfma<<<dim3(TSEQ / 128, NH, BSZ), blk5, 0, stream>>>(qb, kvb, vtb, obuf, causal);
  gemm256<<<dim3(CDIM / 256, BT / 256), blk5, 0, stream>>>(obuf, woT, d_out, CDIM, CDIM, 0);
}